// Round 8
// baseline (211.619 us; speedup 1.0000x reference)
//
#include <hip/hip_runtime.h>
#include <hip/hip_bf16.h>
#include <stdint.h>

typedef __attribute__((ext_vector_type(8))) short bf16x8;   // 8 bf16 (4 VGPRs)
typedef __attribute__((ext_vector_type(4))) short s16x4;
typedef __attribute__((ext_vector_type(4))) float f32x4;

#define MFMA16(a, b, c) __builtin_amdgcn_mfma_f32_16x16x32_bf16((a), (b), (c), 0, 0, 0)
// v_mfma_f32_16x16x16_bf16 — ROCm builtin keeps the gfx90a "_1k" name.
#define MFMAH(a, b, c) __builtin_amdgcn_mfma_f32_16x16x16bf16_1k((a), (b), (c), 0, 0, 0)

__device__ __forceinline__ void gload_lds16(const void* g, void* l) {
  // async global->LDS; HW adds lane*16 to the wave-uniform LDS base
  __builtin_amdgcn_global_load_lds((const __attribute__((address_space(1))) void*)g,
                                   (__attribute__((address_space(3))) void*)l, 16, 0, 0);
}

// ---- all f32->bf16 conversions fused into one grid-stride kernel ----
__global__ void cvt_all(const float* __restrict__ s0, const float* __restrict__ s1,
                        const float* __restrict__ s2, const float* __restrict__ s3,
                        const float* __restrict__ s4, const float* __restrict__ s5,
                        const float* __restrict__ s6,
                        __hip_bfloat16* __restrict__ d0, __hip_bfloat16* __restrict__ d1,
                        __hip_bfloat16* __restrict__ d2, __hip_bfloat16* __restrict__ d3,
                        __hip_bfloat16* __restrict__ d4, __hip_bfloat16* __restrict__ d5,
                        __hip_bfloat16* __restrict__ d6) {
  // region sizes in float4 units (compile-time: x, ctx, Wq, Wk, Wv, P1, P2)
  constexpr int e0 = 2097152;
  constexpr int e1 = e0 + 196608;
  constexpr int e2 = e1 + 131072;
  constexpr int e3 = e2 + 196608;
  constexpr int e4 = e3 + 196608;
  constexpr int e5 = e4 + 262144;
  constexpr int e6 = e5 + 131072;
  const int stride = gridDim.x * blockDim.x;
  for (int i = blockIdx.x * blockDim.x + threadIdx.x; i < e6; i += stride) {
    const float* s; __hip_bfloat16* d; int j;
    if (i < e0)      { s = s0; d = d0; j = i; }
    else if (i < e1) { s = s1; d = d1; j = i - e0; }
    else if (i < e2) { s = s2; d = d2; j = i - e1; }
    else if (i < e3) { s = s3; d = d3; j = i - e2; }
    else if (i < e4) { s = s4; d = d4; j = i - e3; }
    else if (i < e5) { s = s5; d = d5; j = i - e4; }
    else             { s = s6; d = d6; j = i - e5; }
    const float4 v = *(const float4*)(s + (size_t)j * 4);
    s16x4 o;
    __hip_bfloat16 h;
    h = __float2bfloat16(v.x); o[0] = *(short*)&h;
    h = __float2bfloat16(v.y); o[1] = *(short*)&h;
    h = __float2bfloat16(v.z); o[2] = *(short*)&h;
    h = __float2bfloat16(v.w); o[3] = *(short*)&h;
    *(s16x4*)((short*)d + (size_t)j * 4) = o;
  }
}

// C[M,N] = A[M,K] @ W[N,K]^T + bias. 128x128 tile, BK=32, 4 waves (m97 frame).
// OUTMODE: 0 = bf16 row-major; 1 = f32 row-major; 2 = bf16 V^T layout
//          [b*16+h][d][s] (b=row>>8, s=row&255, h=col>>6, d=col&63).
template <int RELU, int OUTMODE>
__global__ __launch_bounds__(256, 2) void gemm_bt(
    const __hip_bfloat16* __restrict__ Abf, const __hip_bfloat16* __restrict__ Wbf,
    const float* __restrict__ bias, void* __restrict__ Cv,
    int M, int N, int K) {
  __shared__ __align__(16) __hip_bfloat16 As[128 * 32];
  __shared__ __align__(16) __hip_bfloat16 Bs[128 * 32];
  const int t = threadIdx.x;
  const int w = t >> 6, lane = t & 63;
  const int lr = lane & 15, lg = lane >> 4;
  const int m0 = blockIdx.x * 128, n0 = blockIdx.y * 128;
  const int wr = (w >> 1) * 64, wc = (w & 1) * 64;

  const char* Ag = (const char*)Abf;
  const char* Wg = (const char*)Wbf;
  const size_t ldb = (size_t)K * 2;

  f32x4 acc[4][4] = {};

  const int o0 = (w << 10) + lane * 16;
  const int o1 = o0 + 4096;
  const int r0 = o0 >> 6, c0 = o0 & 63;
  const int r1 = o1 >> 6, c1 = o1 & 63;

  for (int kt = 0; kt < K; kt += 32) {
    if (kt) __syncthreads();
    gload_lds16(Ag + (size_t)(m0 + r0) * ldb + kt * 2 + c0, (char*)As + (w << 10));
    gload_lds16(Ag + (size_t)(m0 + r1) * ldb + kt * 2 + c1, (char*)As + 4096 + (w << 10));
    gload_lds16(Wg + (size_t)(n0 + r0) * ldb + kt * 2 + c0, (char*)Bs + (w << 10));
    gload_lds16(Wg + (size_t)(n0 + r1) * ldb + kt * 2 + c1, (char*)Bs + 4096 + (w << 10));
    __syncthreads();

    bf16x8 af[4], bfv[4];
#pragma unroll
    for (int mi = 0; mi < 4; ++mi)
      af[mi] = *(const bf16x8*)((const char*)As + ((wr + mi * 16 + lr) << 6) + (lg << 4));
#pragma unroll
    for (int ni = 0; ni < 4; ++ni)
      bfv[ni] = *(const bf16x8*)((const char*)Bs + ((wc + ni * 16 + lr) << 6) + (lg << 4));
#pragma unroll
    for (int mi = 0; mi < 4; ++mi)
#pragma unroll
      for (int ni = 0; ni < 4; ++ni)
        acc[mi][ni] = MFMA16(af[mi], bfv[ni], acc[mi][ni]);
  }

#pragma unroll
  for (int ni = 0; ni < 4; ++ni) {
    const int col = n0 + wc + ni * 16 + lr;
    const float bv = bias[col];
#pragma unroll
    for (int mi = 0; mi < 4; ++mi) {
      const int row = m0 + wr + mi * 16 + lg * 4;
#pragma unroll
      for (int j = 0; j < 4; ++j) {
        float v = acc[mi][ni][j] + bv;
        if (RELU) v = fmaxf(v, 0.0f);
        if (OUTMODE == 0) {
          ((__hip_bfloat16*)Cv)[(size_t)(row + j) * N + col] = __float2bfloat16(v);
        } else if (OUTMODE == 1) {
          ((float*)Cv)[(size_t)(row + j) * N + col] = v;
        } else {
          const int rb = (row + j) >> 8, s = (row + j) & 255;
          const int hh = col >> 6, d = col & 63;
          ((__hip_bfloat16*)Cv)[(((size_t)(rb * 16 + hh) * 64 + d) << 8) + s] =
              __float2bfloat16(v);
        }
      }
    }
  }
}

// 256x256 tile, BK=32, 8 waves (2Mx4N), double-buffered LDS (2x32KB), 2-phase:
// stage(next) || compute(cur), ONE __syncthreads per K-step (drains vmcnt+lgkm).
// Per wave per step: 32 MFMA / 1 barrier (4x the 128^2 kernel's amortization).
template <int RELU>
__global__ __launch_bounds__(512, 2) void gemm256(
    const __hip_bfloat16* __restrict__ Abf, const __hip_bfloat16* __restrict__ Wbf,
    const float* __restrict__ bias, __hip_bfloat16* __restrict__ C,
    int M, int N, int K) {
  __shared__ __align__(16) __hip_bfloat16 As[2][256 * 32];
  __shared__ __align__(16) __hip_bfloat16 Bs[2][256 * 32];
  const int t = threadIdx.x;           // 0..511
  const int w = t >> 6, lane = t & 63;
  const int lr = lane & 15, lg = lane >> 4;
  const int m0 = blockIdx.x * 256, n0 = blockIdx.y * 256;
  const int wr = (w >> 2) * 128, wc = (w & 3) * 64;  // per-wave 128x64 output

  const char* Ag = (const char*)Abf;
  const char* Wg = (const char*)Wbf;
  const size_t ldb = (size_t)K * 2;

  f32x4 acc[8][4] = {};

  // staging: 2 passes x 512 thr x 16B per matrix; 64B rows (32 bf16)
  const int o0 = (w << 10) + lane * 16;   // pass 0 flat byte offset (incl lane)
  const int o1 = o0 + 8192;               // pass 1
  const int r0 = o0 >> 6, c0 = o0 & 63;
  const int r1 = o1 >> 6, c1 = o1 & 63;
  const int db0 = (w << 10);              // wave-uniform LDS dest bases
  const int db1 = 8192 + (w << 10);

  auto STAGE = [&](int buf, int kt) {
    gload_lds16(Ag + (size_t)(m0 + r0) * ldb + kt * 2 + c0, (char*)As[buf] + db0);
    gload_lds16(Ag + (size_t)(m0 + r1) * ldb + kt * 2 + c1, (char*)As[buf] + db1);
    gload_lds16(Wg + (size_t)(n0 + r0) * ldb + kt * 2 + c0, (char*)Bs[buf] + db0);
    gload_lds16(Wg + (size_t)(n0 + r1) * ldb + kt * 2 + c1, (char*)Bs[buf] + db1);
  };
  auto COMPUTE = [&](int buf) {
    bf16x8 af[8], bfv[4];
#pragma unroll
    for (int mi = 0; mi < 8; ++mi)
      af[mi] = *(const bf16x8*)((const char*)As[buf] + ((wr + mi * 16 + lr) << 6) + (lg << 4));
#pragma unroll
    for (int ni = 0; ni < 4; ++ni)
      bfv[ni] = *(const bf16x8*)((const char*)Bs[buf] + ((wc + ni * 16 + lr) << 6) + (lg << 4));
#pragma unroll
    for (int mi = 0; mi < 8; ++mi)
#pragma unroll
      for (int ni = 0; ni < 4; ++ni)
        acc[mi][ni] = MFMA16(af[mi], bfv[ni], acc[mi][ni]);
  };

  STAGE(0, 0);
  __syncthreads();
  int cur = 0;
  for (int kt = 32; kt < K; kt += 32) {
    STAGE(cur ^ 1, kt);   // async loads fly while we compute cur
    COMPUTE(cur);
    __syncthreads();      // drains vmcnt(0)+lgkmcnt(0), then barrier
    cur ^= 1;
  }
  COMPUTE(cur);

#pragma unroll
  for (int ni = 0; ni < 4; ++ni) {
    const int col = n0 + wc + ni * 16 + lr;
    const float bv = bias[col];
#pragma unroll
    for (int mi = 0; mi < 8; ++mi) {
      const int row = m0 + wr + mi * 16 + lg * 4;
#pragma unroll
      for (int j = 0; j < 4; ++j) {
        float v = acc[mi][ni][j] + bv;
        if (RELU) v = fmaxf(v, 0.0f);
        C[(size_t)(row + j) * N + col] = __float2bfloat16(v);
      }
    }
  }
}

// Fused cross-attention (round-7, frozen): swapped QK^T, register P, 16x16x16 PV.
__global__ __launch_bounds__(256, 2) void attn_fused(
    const __hip_bfloat16* __restrict__ Qb, const __hip_bfloat16* __restrict__ Kb,
    const __hip_bfloat16* __restrict__ Vtg, const float* __restrict__ padm,
    const float* __restrict__ seqm, __hip_bfloat16* __restrict__ O) {
  constexpr int S = 256, E = 1024, Nq = 4096;
  constexpr float NEGV = -1e9f;
  __shared__ __align__(16) char smem[65536];
  char* VtB = smem;
  char* KsB = smem + 32768;

  const int t = threadIdx.x;
  const int w = t >> 6, lane = t & 63;
  const int lr = lane & 15, lg = lane >> 4;
  const int h = blockIdx.y, b = blockIdx.z;

  const char* Kg = (const char*)(Kb + (size_t)b * S * E + h * 64);
#pragma unroll
  for (int i = 0; i < 8; ++i) {
    const int o = ((i * 4 + w) << 10) + lane * 16;
    const int s = o >> 7, bc = o & 127;
    gload_lds16(Kg + (size_t)s * (E * 2) + (bc ^ ((s & 7) << 4)), KsB + ((i * 4 + w) << 10));
  }
  const char* Vg = (const char*)Vtg + ((size_t)(b * 16 + h) << 15);
#pragma unroll
  for (int i = 0; i < 8; ++i) {
    const int o = ((i * 4 + w) << 10) + lane * 16;
    const int d = o >> 9, c = o & 511;
    gload_lds16(Vg + (d << 9) + (c ^ ((d & 7) << 4)), VtB + ((i * 4 + w) << 10));
  }

  const int qw = blockIdx.x * 64 + w * 16;
  const short* Qg = (const short*)Qb + (size_t)(b * Nq + qw + lr) * E + h * 64;
  const bf16x8 aq0 = *(const bf16x8*)(Qg + (lg << 3));
  const bf16x8 aq1 = *(const bf16x8*)(Qg + 32 + (lg << 3));
  const float padq = padm[(size_t)b * Nq + qw + lr];
  const float qbias = (padq != 0.f) ? 0.f : NEGV;

  __syncthreads();

  const int swz = (lr & 7) << 4;
  f32x4 o[4] = {};
  float ssum = 0.f;
#pragma unroll
  for (int ni = 0; ni < 16; ++ni) {
    const int s = ni * 16 + lr;
    const bf16x8 bk0 = *(const bf16x8*)(KsB + (s << 7) + ((lg << 4) ^ swz));
    const bf16x8 bk1 = *(const bf16x8*)(KsB + (s << 7) + ((64 + (lg << 4)) ^ swz));
    f32x4 a = {};
    a = MFMA16(bk0, aq0, a);
    a = MFMA16(bk1, aq1, a);

    const float4 sm4 = *(const float4*)(seqm + (size_t)b * S + ni * 16 + lg * 4);
    const float e0 = __expf(a[0] * 0.125f + ((sm4.x != 0.f ? 0.f : NEGV) + qbias));
    const float e1 = __expf(a[1] * 0.125f + ((sm4.y != 0.f ? 0.f : NEGV) + qbias));
    const float e2 = __expf(a[2] * 0.125f + ((sm4.z != 0.f ? 0.f : NEGV) + qbias));
    const float e3 = __expf(a[3] * 0.125f + ((sm4.w != 0.f ? 0.f : NEGV) + qbias));
    ssum += (e0 + e1) + (e2 + e3);

    s16x4 pf;
    __hip_bfloat16 hh;
    hh = __float2bfloat16(e0); pf[0] = *(short*)&hh;
    hh = __float2bfloat16(e1); pf[1] = *(short*)&hh;
    hh = __float2bfloat16(e2); pf[2] = *(short*)&hh;
    hh = __float2bfloat16(e3); pf[3] = *(short*)&hh;

    const int sb = (ni * 32 + lg * 8);
#pragma unroll
    for (int nd = 0; nd < 4; ++nd) {
      const int d = nd * 16 + lr;
      const s16x4 bv = *(const s16x4*)(VtB + (d << 9) + (sb ^ swz));
      o[nd] = MFMAH(pf, bv, o[nd]);
    }
  }

  ssum += __shfl_xor(ssum, 16);
  ssum += __shfl_xor(ssum, 32);
  const float inv = 1.0f / ssum;
  float invj[4];
#pragma unroll
  for (int j = 0; j < 4; ++j) invj[j] = __shfl(inv, lg * 4 + j);

  __hip_bfloat16* Og = O + (size_t)(b * Nq + qw) * E + h * 64;
#pragma unroll
  for (int nd = 0; nd < 4; ++nd)
#pragma unroll
    for (int j = 0; j < 4; ++j)
      Og[(size_t)(lg * 4 + j) * E + nd * 16 + lr] = __float2bfloat16(o[nd][j] * invj[j]);
}

extern "C" void kernel_launch(void* const* d_in, const int* in_sizes, int n_in,
                              void* d_out, int out_size, void* d_ws, size_t ws_size,
                              hipStream_t stream) {
  const float* x    = (const float*)d_in[0];
  const float* ctx  = (const float*)d_in[1];
  const float* padm = (const float*)d_in[2];
  const float* seqm = (const float*)d_in[3];
  const float* Wq_w = (const float*)d_in[4];
  const float* Wq_b = (const float*)d_in[5];
  const float* Wk_w = (const float*)d_in[6];
  const float* Wk_b = (const float*)d_in[7];
  const float* Wv_w = (const float*)d_in[8];
  const float* Wv_b = (const float*)d_in[9];
  const float* P1_w = (const float*)d_in[10];
  const float* P1_b = (const float*)d_in[11];
  const float* P2_w = (const float*)d_in[12];
  const float* P2_b = (const float*)d_in[13];
  float* out = (float*)d_out;

  char* ws = (char*)d_ws;
  size_t off = 0;
  auto alloc = [&](size_t bytes) { char* p = ws + off; off += (bytes + 255) & ~(size_t)255; return p; };
  __hip_bfloat16* Q    = (__hip_bfloat16*)alloc(16384ull * 1024 * 2);  // 32MB (later O1)
  __hip_bfloat16* AO   = (__hip_bfloat16*)alloc(16384ull * 1024 * 2);  // 32MB
  __hip_bfloat16* xb   = (__hip_bfloat16*)alloc(16384ull * 512 * 2);   // 16MB
  __hip_bfloat16* ctxb = (__hip_bfloat16*)alloc(1024ull * 768 * 2);
  __hip_bfloat16* Kp   = (__hip_bfloat16*)alloc(1024ull * 1024 * 2);
  __hip_bfloat16* Vt   = (__hip_bfloat16*)alloc(1024ull * 1024 * 2);   // V^T [b,h][d][s]
  __hip_bfloat16* Wqb  = (__hip_bfloat16*)alloc(1024ull * 512 * 2);
  __hip_bfloat16* Wkb  = (__hip_bfloat16*)alloc(1024ull * 768 * 2);
  __hip_bfloat16* Wvb  = (__hip_bfloat16*)alloc(1024ull * 768 * 2);
  __hip_bfloat16* P1b  = (__hip_bfloat16*)alloc(1024ull * 1024 * 2);
  __hip_bfloat16* P2b  = (__hip_bfloat16*)alloc(512ull * 1024 * 2);
  __hip_bfloat16* O1   = Q;  // reuse Q after attention

  cvt_all<<<dim3(2048, 1, 1), dim3(256, 1, 1), 0, stream>>>(
      x, ctx, Wq_w, Wk_w, Wv_w, P1_w, P2_w, xb, ctxb, Wqb, Wkb, Wvb, P1b, P2b);

  const dim3 blk(256, 1, 1);
  gemm256<0><<<dim3(64, 4, 1), dim3(512, 1, 1), 0, stream>>>(xb, Wqb, Wq_b, Q, 16384, 1024, 512);
  gemm_bt<0, 0><<<dim3(8, 8, 1), blk, 0, stream>>>(ctxb, Wkb, Wk_b, Kp, 1024, 1024, 768);
  gemm_bt<0, 2><<<dim3(8, 8, 1), blk, 0, stream>>>(ctxb, Wvb, Wv_b, Vt, 1024, 1024, 768);
  attn_fused<<<dim3(64, 16, 4), blk, 0, stream>>>(Q, Kp, Vt, padm, seqm, AO);
  gemm256<1><<<dim3(64, 4, 1), dim3(512, 1, 1), 0, stream>>>(AO, P1b, P1_b, O1, 16384, 1024, 1024);
  gemm_bt<0, 1><<<dim3(128, 4, 1), blk, 0, stream>>>(O1, P2b, P2_b, out, 16384, 512, 1024);
}

// Round 9
// 204.808 us; speedup vs baseline: 1.0333x; 1.0333x over previous
//
#include <hip/hip_runtime.h>
#include <hip/hip_bf16.h>
#include <stdint.h>

typedef __attribute__((ext_vector_type(8))) short bf16x8;   // 8 bf16 (4 VGPRs)
typedef __attribute__((ext_vector_type(4))) short s16x4;
typedef __attribute__((ext_vector_type(4))) float f32x4;

#define MFMA16(a, b, c) __builtin_amdgcn_mfma_f32_16x16x32_bf16((a), (b), (c), 0, 0, 0)
// v_mfma_f32_16x16x16_bf16 — ROCm builtin keeps the gfx90a "_1k" name.
#define MFMAH(a, b, c) __builtin_amdgcn_mfma_f32_16x16x16bf16_1k((a), (b), (c), 0, 0, 0)

__device__ __forceinline__ void gload_lds16(const void* g, void* l) {
  // async global->LDS; HW adds lane*16 to the wave-uniform LDS base
  __builtin_amdgcn_global_load_lds((const __attribute__((address_space(1))) void*)g,
                                   (__attribute__((address_space(3))) void*)l, 16, 0, 0);
}

// ---- all f32->bf16 conversions fused into one grid-stride kernel ----
__global__ void cvt_all(const float* __restrict__ s0, const float* __restrict__ s1,
                        const float* __restrict__ s2, const float* __restrict__ s3,
                        const float* __restrict__ s4, const float* __restrict__ s5,
                        const float* __restrict__ s6,
                        __hip_bfloat16* __restrict__ d0, __hip_bfloat16* __restrict__ d1,
                        __hip_bfloat16* __restrict__ d2, __hip_bfloat16* __restrict__ d3,
                        __hip_bfloat16* __restrict__ d4, __hip_bfloat16* __restrict__ d5,
                        __hip_bfloat16* __restrict__ d6) {
  constexpr int e0 = 2097152;
  constexpr int e1 = e0 + 196608;
  constexpr int e2 = e1 + 131072;
  constexpr int e3 = e2 + 196608;
  constexpr int e4 = e3 + 196608;
  constexpr int e5 = e4 + 262144;
  constexpr int e6 = e5 + 131072;
  const int stride = gridDim.x * blockDim.x;
  for (int i = blockIdx.x * blockDim.x + threadIdx.x; i < e6; i += stride) {
    const float* s; __hip_bfloat16* d; int j;
    if (i < e0)      { s = s0; d = d0; j = i; }
    else if (i < e1) { s = s1; d = d1; j = i - e0; }
    else if (i < e2) { s = s2; d = d2; j = i - e1; }
    else if (i < e3) { s = s3; d = d3; j = i - e2; }
    else if (i < e4) { s = s4; d = d4; j = i - e3; }
    else if (i < e5) { s = s5; d = d5; j = i - e4; }
    else             { s = s6; d = d6; j = i - e5; }
    const float4 v = *(const float4*)(s + (size_t)j * 4);
    s16x4 o;
    __hip_bfloat16 h;
    h = __float2bfloat16(v.x); o[0] = *(short*)&h;
    h = __float2bfloat16(v.y); o[1] = *(short*)&h;
    h = __float2bfloat16(v.z); o[2] = *(short*)&h;
    h = __float2bfloat16(v.w); o[3] = *(short*)&h;
    *(s16x4*)((short*)d + (size_t)j * 4) = o;
  }
}

// C[M,N] = A[M,K] @ W[N,K]^T + bias. 128x128 tile, BK=32, 4 waves (m97 frame).
// OUTMODE: 0 = bf16 row-major; 1 = f32 row-major; 2 = bf16 V^T layout.
template <int RELU, int OUTMODE>
__global__ __launch_bounds__(256, 2) void gemm_bt(
    const __hip_bfloat16* __restrict__ Abf, const __hip_bfloat16* __restrict__ Wbf,
    const float* __restrict__ bias, void* __restrict__ Cv,
    int M, int N, int K) {
  __shared__ __align__(16) __hip_bfloat16 As[128 * 32];
  __shared__ __align__(16) __hip_bfloat16 Bs[128 * 32];
  const int t = threadIdx.x;
  const int w = t >> 6, lane = t & 63;
  const int lr = lane & 15, lg = lane >> 4;
  const int m0 = blockIdx.x * 128, n0 = blockIdx.y * 128;
  const int wr = (w >> 1) * 64, wc = (w & 1) * 64;

  const char* Ag = (const char*)Abf;
  const char* Wg = (const char*)Wbf;
  const size_t ldb = (size_t)K * 2;

  f32x4 acc[4][4] = {};

  const int o0 = (w << 10) + lane * 16;
  const int o1 = o0 + 4096;
  const int r0 = o0 >> 6, c0 = o0 & 63;
  const int r1 = o1 >> 6, c1 = o1 & 63;

  for (int kt = 0; kt < K; kt += 32) {
    if (kt) __syncthreads();
    gload_lds16(Ag + (size_t)(m0 + r0) * ldb + kt * 2 + c0, (char*)As + (w << 10));
    gload_lds16(Ag + (size_t)(m0 + r1) * ldb + kt * 2 + c1, (char*)As + 4096 + (w << 10));
    gload_lds16(Wg + (size_t)(n0 + r0) * ldb + kt * 2 + c0, (char*)Bs + (w << 10));
    gload_lds16(Wg + (size_t)(n0 + r1) * ldb + kt * 2 + c1, (char*)Bs + 4096 + (w << 10));
    __syncthreads();

    bf16x8 af[4], bfv[4];
#pragma unroll
    for (int mi = 0; mi < 4; ++mi)
      af[mi] = *(const bf16x8*)((const char*)As + ((wr + mi * 16 + lr) << 6) + (lg << 4));
#pragma unroll
    for (int ni = 0; ni < 4; ++ni)
      bfv[ni] = *(const bf16x8*)((const char*)Bs + ((wc + ni * 16 + lr) << 6) + (lg << 4));
#pragma unroll
    for (int mi = 0; mi < 4; ++mi)
#pragma unroll
      for (int ni = 0; ni < 4; ++ni)
        acc[mi][ni] = MFMA16(af[mi], bfv[ni], acc[mi][ni]);
  }

#pragma unroll
  for (int ni = 0; ni < 4; ++ni) {
    const int col = n0 + wc + ni * 16 + lr;
    const float bv = bias[col];
#pragma unroll
    for (int mi = 0; mi < 4; ++mi) {
      const int row = m0 + wr + mi * 16 + lg * 4;
#pragma unroll
      for (int j = 0; j < 4; ++j) {
        float v = acc[mi][ni][j] + bv;
        if (RELU) v = fmaxf(v, 0.0f);
        if (OUTMODE == 0) {
          ((__hip_bfloat16*)Cv)[(size_t)(row + j) * N + col] = __float2bfloat16(v);
        } else if (OUTMODE == 1) {
          ((float*)Cv)[(size_t)(row + j) * N + col] = v;
        } else {
          const int rb = (row + j) >> 8, s = (row + j) & 255;
          const int hh = col >> 6, d = col & 63;
          ((__hip_bfloat16*)Cv)[(((size_t)(rb * 16 + hh) * 64 + d) << 8) + s] =
              __float2bfloat16(v);
        }
      }
    }
  }
}

// 256x256 tile, BK=32, 8 waves, 4-buffer LDS pipeline (128KB), counted vmcnt:
// per K-step: STAGE(tile j+3) -> vmcnt(12) -> s_barrier -> COMPUTE(tile j)
// -> s_barrier. Loads for tiles j+1..j+3 stay in flight across barriers (T4);
// depth-3 prefetch (~3 compute phases ~ 1000 cyc) covers HBM latency.
// Safety: own-vmcnt+barrier => all waves' tile-j loads landed; post-compute
// barrier => buffer free before iter j+4 overwrites it. No other VMEM ops in
// the loop, so vmcnt counts are exact.
template <int RELU>
__global__ __launch_bounds__(512, 2) void gemm256(
    const __hip_bfloat16* __restrict__ Abf, const __hip_bfloat16* __restrict__ Wbf,
    const float* __restrict__ bias, __hip_bfloat16* __restrict__ C,
    int M, int N, int K) {
  __shared__ __align__(16) __hip_bfloat16 AsB[4][256 * 32];  // 4 x 16KB
  __shared__ __align__(16) __hip_bfloat16 BsB[4][256 * 32];  // 4 x 16KB
  const int t = threadIdx.x;           // 0..511
  const int w = t >> 6, lane = t & 63;
  const int lr = lane & 15, lg = lane >> 4;
  const int m0 = blockIdx.x * 256, n0 = blockIdx.y * 256;
  const int wr = (w >> 2) * 128, wc = (w & 3) * 64;  // per-wave 128x64 output

  const char* Ag = (const char*)Abf;
  const char* Wg = (const char*)Wbf;
  const size_t ldb = (size_t)K * 2;

  f32x4 acc[8][4] = {};

  // staging: 2 passes x 512 thr x 16B per matrix; 64B rows (32 bf16)
  const int o0 = (w << 10) + lane * 16;
  const int o1 = o0 + 8192;
  const int r0 = o0 >> 6, c0 = o0 & 63;
  const int r1 = o1 >> 6, c1 = o1 & 63;
  const int db0 = (w << 10);
  const int db1 = 8192 + (w << 10);

  auto STAGE = [&](int buf, int tile) {
    const int kt = tile << 5;
    gload_lds16(Ag + (size_t)(m0 + r0) * ldb + kt * 2 + c0, (char*)AsB[buf] + db0);
    gload_lds16(Ag + (size_t)(m0 + r1) * ldb + kt * 2 + c1, (char*)AsB[buf] + db1);
    gload_lds16(Wg + (size_t)(n0 + r0) * ldb + kt * 2 + c0, (char*)BsB[buf] + db0);
    gload_lds16(Wg + (size_t)(n0 + r1) * ldb + kt * 2 + c1, (char*)BsB[buf] + db1);
  };
  auto COMPUTE = [&](int buf) {
    bf16x8 af[8], bfv[4];
#pragma unroll
    for (int mi = 0; mi < 8; ++mi)
      af[mi] = *(const bf16x8*)((const char*)AsB[buf] + ((wr + mi * 16 + lr) << 6) + (lg << 4));
#pragma unroll
    for (int ni = 0; ni < 4; ++ni)
      bfv[ni] = *(const bf16x8*)((const char*)BsB[buf] + ((wc + ni * 16 + lr) << 6) + (lg << 4));
#pragma unroll
    for (int mi = 0; mi < 8; ++mi)
#pragma unroll
      for (int ni = 0; ni < 4; ++ni)
        acc[mi][ni] = MFMA16(af[mi], bfv[ni], acc[mi][ni]);
  };

  const int nt = K >> 5;  // #K-tiles (16 or 32; >= 4)
  STAGE(0, 0);
  STAGE(1, 1);
  STAGE(2, 2);
  for (int j = 0; j < nt - 3; ++j) {
    STAGE((j + 3) & 3, j + 3);
    asm volatile("s_waitcnt vmcnt(12)" ::: "memory");
    __builtin_amdgcn_s_barrier();
    COMPUTE(j & 3);
    __builtin_amdgcn_s_barrier();
  }
  asm volatile("s_waitcnt vmcnt(8)" ::: "memory");
  __builtin_amdgcn_s_barrier();
  COMPUTE((nt - 3) & 3);
  __builtin_amdgcn_s_barrier();
  asm volatile("s_waitcnt vmcnt(4)" ::: "memory");
  __builtin_amdgcn_s_barrier();
  COMPUTE((nt - 2) & 3);
  __builtin_amdgcn_s_barrier();
  asm volatile("s_waitcnt vmcnt(0)" ::: "memory");
  __builtin_amdgcn_s_barrier();
  COMPUTE((nt - 1) & 3);

#pragma unroll
  for (int ni = 0; ni < 4; ++ni) {
    const int col = n0 + wc + ni * 16 + lr;
    const float bv = bias[col];
#pragma unroll
    for (int mi = 0; mi < 8; ++mi) {
      const int row = m0 + wr + mi * 16 + lg * 4;
#pragma unroll
      for (int j = 0; j < 4; ++j) {
        float v = acc[mi][ni][j] + bv;
        if (RELU) v = fmaxf(v, 0.0f);
        C[(size_t)(row + j) * N + col] = __float2bfloat16(v);
      }
    }
  }
}

// Fused cross-attention (round-7, frozen): swapped QK^T, register P, 16x16x16 PV.
__global__ __launch_bounds__(256, 2) void attn_fused(
    const __hip_bfloat16* __restrict__ Qb, const __hip_bfloat16* __restrict__ Kb,
    const __hip_bfloat16* __restrict__ Vtg, const float* __restrict__ padm,
    const float* __restrict__ seqm, __hip_bfloat16* __restrict__ O) {
  constexpr int S = 256, E = 1024, Nq = 4096;
  constexpr float NEGV = -1e9f;
  __shared__ __align__(16) char smem[65536];
  char* VtB = smem;
  char* KsB = smem + 32768;

  const int t = threadIdx.x;
  const int w = t >> 6, lane = t & 63;
  const int lr = lane & 15, lg = lane >> 4;
  const int h = blockIdx.y, b = blockIdx.z;

  const char* Kg = (const char*)(Kb + (size_t)b * S * E + h * 64);
#pragma unroll
  for (int i = 0; i < 8; ++i) {
    const int o = ((i * 4 + w) << 10) + lane * 16;
    const int s = o >> 7, bc = o & 127;
    gload_lds16(Kg + (size_t)s * (E * 2) + (bc ^ ((s & 7) << 4)), KsB + ((i * 4 + w) << 10));
  }
  const char* Vg = (const char*)Vtg + ((size_t)(b * 16 + h) << 15);
#pragma unroll
  for (int i = 0; i < 8; ++i) {
    const int o = ((i * 4 + w) << 10) + lane * 16;
    const int d = o >> 9, c = o & 511;
    gload_lds16(Vg + (d << 9) + (c ^ ((d & 7) << 4)), VtB + ((i * 4 + w) << 10));
  }

  const int qw = blockIdx.x * 64 + w * 16;
  const short* Qg = (const short*)Qb + (size_t)(b * Nq + qw + lr) * E + h * 64;
  const bf16x8 aq0 = *(const bf16x8*)(Qg + (lg << 3));
  const bf16x8 aq1 = *(const bf16x8*)(Qg + 32 + (lg << 3));
  const float padq = padm[(size_t)b * Nq + qw + lr];
  const float qbias = (padq != 0.f) ? 0.f : NEGV;

  __syncthreads();

  const int swz = (lr & 7) << 4;
  f32x4 o[4] = {};
  float ssum = 0.f;
#pragma unroll
  for (int ni = 0; ni < 16; ++ni) {
    const int s = ni * 16 + lr;
    const bf16x8 bk0 = *(const bf16x8*)(KsB + (s << 7) + ((lg << 4) ^ swz));
    const bf16x8 bk1 = *(const bf16x8*)(KsB + (s << 7) + ((64 + (lg << 4)) ^ swz));
    f32x4 a = {};
    a = MFMA16(bk0, aq0, a);
    a = MFMA16(bk1, aq1, a);

    const float4 sm4 = *(const float4*)(seqm + (size_t)b * S + ni * 16 + lg * 4);
    const float e0 = __expf(a[0] * 0.125f + ((sm4.x != 0.f ? 0.f : NEGV) + qbias));
    const float e1 = __expf(a[1] * 0.125f + ((sm4.y != 0.f ? 0.f : NEGV) + qbias));
    const float e2 = __expf(a[2] * 0.125f + ((sm4.z != 0.f ? 0.f : NEGV) + qbias));
    const float e3 = __expf(a[3] * 0.125f + ((sm4.w != 0.f ? 0.f : NEGV) + qbias));
    ssum += (e0 + e1) + (e2 + e3);

    s16x4 pf;
    __hip_bfloat16 hh;
    hh = __float2bfloat16(e0); pf[0] = *(short*)&hh;
    hh = __float2bfloat16(e1); pf[1] = *(short*)&hh;
    hh = __float2bfloat16(e2); pf[2] = *(short*)&hh;
    hh = __float2bfloat16(e3); pf[3] = *(short*)&hh;

    const int sb = (ni * 32 + lg * 8);
#pragma unroll
    for (int nd = 0; nd < 4; ++nd) {
      const int d = nd * 16 + lr;
      const s16x4 bv = *(const s16x4*)(VtB + (d << 9) + (sb ^ swz));
      o[nd] = MFMAH(pf, bv, o[nd]);
    }
  }

  ssum += __shfl_xor(ssum, 16);
  ssum += __shfl_xor(ssum, 32);
  const float inv = 1.0f / ssum;
  float invj[4];
#pragma unroll
  for (int j = 0; j < 4; ++j) invj[j] = __shfl(inv, lg * 4 + j);

  __hip_bfloat16* Og = O + (size_t)(b * Nq + qw) * E + h * 64;
#pragma unroll
  for (int nd = 0; nd < 4; ++nd)
#pragma unroll
    for (int j = 0; j < 4; ++j)
      Og[(size_t)(lg * 4 + j) * E + nd * 16 + lr] = __float2bfloat16(o[nd][j] * invj[j]);
}

extern "C" void kernel_launch(void* const* d_in, const int* in_sizes, int n_in,
                              void* d_out, int out_size, void* d_ws, size_t ws_size,
                              hipStream_t stream) {
  const float* x    = (const float*)d_in[0];
  const float* ctx  = (const float*)d_in[1];
  const float* padm = (const float*)d_in[2];
  const float* seqm = (const float*)d_in[3];
  const float* Wq_w = (const float*)d_in[4];
  const float* Wq_b = (const float*)d_in[5];
  const float* Wk_w = (const float*)d_in[6];
  const float* Wk_b = (const float*)d_in[7];
  const float* Wv_w = (const float*)d_in[8];
  const float* Wv_b = (const float*)d_in[9];
  const float* P1_w = (const float*)d_in[10];
  const float* P1_b = (const float*)d_in[11];
  const float* P2_w = (const float*)d_in[12];
  const float* P2_b = (const float*)d_in[13];
  float* out = (float*)d_out;

  char* ws = (char*)d_ws;
  size_t off = 0;
  auto alloc = [&](size_t bytes) { char* p = ws + off; off += (bytes + 255) & ~(size_t)255; return p; };
  __hip_bfloat16* Q    = (__hip_bfloat16*)alloc(16384ull * 1024 * 2);  // 32MB (later O1)
  __hip_bfloat16* AO   = (__hip_bfloat16*)alloc(16384ull * 1024 * 2);  // 32MB
  __hip_bfloat16* xb   = (__hip_bfloat16*)alloc(16384ull * 512 * 2);   // 16MB
  __hip_bfloat16* ctxb = (__hip_bfloat16*)alloc(1024ull * 768 * 2);
  __hip_bfloat16* Kp   = (__hip_bfloat16*)alloc(1024ull * 1024 * 2);
  __hip_bfloat16* Vt   = (__hip_bfloat16*)alloc(1024ull * 1024 * 2);   // V^T [b,h][d][s]
  __hip_bfloat16* Wqb  = (__hip_bfloat16*)alloc(1024ull * 512 * 2);
  __hip_bfloat16* Wkb  = (__hip_bfloat16*)alloc(1024ull * 768 * 2);
  __hip_bfloat16* Wvb  = (__hip_bfloat16*)alloc(1024ull * 768 * 2);
  __hip_bfloat16* P1b  = (__hip_bfloat16*)alloc(1024ull * 1024 * 2);
  __hip_bfloat16* P2b  = (__hip_bfloat16*)alloc(512ull * 1024 * 2);
  __hip_bfloat16* O1   = Q;  // reuse Q after attention

  cvt_all<<<dim3(2048, 1, 1), dim3(256, 1, 1), 0, stream>>>(
      x, ctx, Wq_w, Wk_w, Wv_w, P1_w, P2_w, xb, ctxb, Wqb, Wkb, Wvb, P1b, P2b);

  const dim3 blk(256, 1, 1);
  gemm256<0><<<dim3(64, 4, 1), dim3(512, 1, 1), 0, stream>>>(xb, Wqb, Wq_b, Q, 16384, 1024, 512);
  gemm_bt<0, 0><<<dim3(8, 8, 1), blk, 0, stream>>>(ctxb, Wkb, Wk_b, Kp, 1024, 1024, 768);
  gemm_bt<0, 2><<<dim3(8, 8, 1), blk, 0, stream>>>(ctxb, Wvb, Wv_b, Vt, 1024, 1024, 768);
  attn_fused<<<dim3(64, 16, 4), blk, 0, stream>>>(Q, Kp, Vt, padm, seqm, AO);
  gemm256<1><<<dim3(64, 4, 1), dim3(512, 1, 1), 0, stream>>>(AO, P1b, P1_b, O1, 16384, 1024, 1024);
  gemm_bt<0, 1><<<dim3(128, 4, 1), blk, 0, stream>>>(O1, P2b, P2_b, out, 16384, 512, 1024);
}

// Round 10
// 172.736 us; speedup vs baseline: 1.2251x; 1.1857x over previous
//
#include <hip/hip_runtime.h>
#include <hip/hip_bf16.h>
#include <stdint.h>

typedef __attribute__((ext_vector_type(8))) short bf16x8;   // 8 bf16 (4 VGPRs)
typedef __attribute__((ext_vector_type(4))) short s16x4;
typedef __attribute__((ext_vector_type(4))) float f32x4;

#define MFMA16(a, b, c) __builtin_amdgcn_mfma_f32_16x16x32_bf16((a), (b), (c), 0, 0, 0)
// v_mfma_f32_16x16x16_bf16 — ROCm builtin keeps the gfx90a "_1k" name.
#define MFMAH(a, b, c) __builtin_amdgcn_mfma_f32_16x16x16bf16_1k((a), (b), (c), 0, 0, 0)

__device__ __forceinline__ void gload_lds16(const void* g, void* l) {
  // async global->LDS; HW adds lane*16 to the wave-uniform LDS base
  __builtin_amdgcn_global_load_lds((const __attribute__((address_space(1))) void*)g,
                                   (__attribute__((address_space(3))) void*)l, 16, 0, 0);
}

// ---- all f32->bf16 conversions fused into one grid-stride kernel ----
__global__ void cvt_all(const float* __restrict__ s0, const float* __restrict__ s1,
                        const float* __restrict__ s2, const float* __restrict__ s3,
                        const float* __restrict__ s4, const float* __restrict__ s5,
                        const float* __restrict__ s6,
                        __hip_bfloat16* __restrict__ d0, __hip_bfloat16* __restrict__ d1,
                        __hip_bfloat16* __restrict__ d2, __hip_bfloat16* __restrict__ d3,
                        __hip_bfloat16* __restrict__ d4, __hip_bfloat16* __restrict__ d5,
                        __hip_bfloat16* __restrict__ d6) {
  constexpr int e0 = 2097152;
  constexpr int e1 = e0 + 196608;
  constexpr int e2 = e1 + 131072;
  constexpr int e3 = e2 + 196608;
  constexpr int e4 = e3 + 196608;
  constexpr int e5 = e4 + 262144;
  constexpr int e6 = e5 + 131072;
  const int stride = gridDim.x * blockDim.x;
  for (int i = blockIdx.x * blockDim.x + threadIdx.x; i < e6; i += stride) {
    const float* s; __hip_bfloat16* d; int j;
    if (i < e0)      { s = s0; d = d0; j = i; }
    else if (i < e1) { s = s1; d = d1; j = i - e0; }
    else if (i < e2) { s = s2; d = d2; j = i - e1; }
    else if (i < e3) { s = s3; d = d3; j = i - e2; }
    else if (i < e4) { s = s4; d = d4; j = i - e3; }
    else if (i < e5) { s = s5; d = d5; j = i - e4; }
    else             { s = s6; d = d6; j = i - e5; }
    const float4 v = *(const float4*)(s + (size_t)j * 4);
    s16x4 o;
    __hip_bfloat16 h;
    h = __float2bfloat16(v.x); o[0] = *(short*)&h;
    h = __float2bfloat16(v.y); o[1] = *(short*)&h;
    h = __float2bfloat16(v.z); o[2] = *(short*)&h;
    h = __float2bfloat16(v.w); o[3] = *(short*)&h;
    *(s16x4*)((short*)d + (size_t)j * 4) = o;
  }
}

// C[M,N] = A[M,K] @ W[N,K]^T + bias. 128x128 tile, BK=32, 4 waves (m97 frame).
// OUTMODE: 0 = bf16 row-major; 1 = f32 row-major; 2 = bf16 V^T layout.
template <int RELU, int OUTMODE>
__global__ __launch_bounds__(256, 2) void gemm_bt(
    const __hip_bfloat16* __restrict__ Abf, const __hip_bfloat16* __restrict__ Wbf,
    const float* __restrict__ bias, void* __restrict__ Cv,
    int M, int N, int K) {
  __shared__ __align__(16) __hip_bfloat16 As[128 * 32];
  __shared__ __align__(16) __hip_bfloat16 Bs[128 * 32];
  const int t = threadIdx.x;
  const int w = t >> 6, lane = t & 63;
  const int lr = lane & 15, lg = lane >> 4;
  const int m0 = blockIdx.x * 128, n0 = blockIdx.y * 128;
  const int wr = (w >> 1) * 64, wc = (w & 1) * 64;

  const char* Ag = (const char*)Abf;
  const char* Wg = (const char*)Wbf;
  const size_t ldb = (size_t)K * 2;

  f32x4 acc[4][4] = {};

  const int o0 = (w << 10) + lane * 16;
  const int o1 = o0 + 4096;
  const int r0 = o0 >> 6, c0 = o0 & 63;
  const int r1 = o1 >> 6, c1 = o1 & 63;

  for (int kt = 0; kt < K; kt += 32) {
    if (kt) __syncthreads();
    gload_lds16(Ag + (size_t)(m0 + r0) * ldb + kt * 2 + c0, (char*)As + (w << 10));
    gload_lds16(Ag + (size_t)(m0 + r1) * ldb + kt * 2 + c1, (char*)As + 4096 + (w << 10));
    gload_lds16(Wg + (size_t)(n0 + r0) * ldb + kt * 2 + c0, (char*)Bs + (w << 10));
    gload_lds16(Wg + (size_t)(n0 + r1) * ldb + kt * 2 + c1, (char*)Bs + 4096 + (w << 10));
    __syncthreads();

    bf16x8 af[4], bfv[4];
#pragma unroll
    for (int mi = 0; mi < 4; ++mi)
      af[mi] = *(const bf16x8*)((const char*)As + ((wr + mi * 16 + lr) << 6) + (lg << 4));
#pragma unroll
    for (int ni = 0; ni < 4; ++ni)
      bfv[ni] = *(const bf16x8*)((const char*)Bs + ((wc + ni * 16 + lr) << 6) + (lg << 4));
#pragma unroll
    for (int mi = 0; mi < 4; ++mi)
#pragma unroll
      for (int ni = 0; ni < 4; ++ni)
        acc[mi][ni] = MFMA16(af[mi], bfv[ni], acc[mi][ni]);
  }

#pragma unroll
  for (int ni = 0; ni < 4; ++ni) {
    const int col = n0 + wc + ni * 16 + lr;
    const float bv = bias[col];
#pragma unroll
    for (int mi = 0; mi < 4; ++mi) {
      const int row = m0 + wr + mi * 16 + lg * 4;
#pragma unroll
      for (int j = 0; j < 4; ++j) {
        float v = acc[mi][ni][j] + bv;
        if (RELU) v = fmaxf(v, 0.0f);
        if (OUTMODE == 0) {
          ((__hip_bfloat16*)Cv)[(size_t)(row + j) * N + col] = __float2bfloat16(v);
        } else if (OUTMODE == 1) {
          ((float*)Cv)[(size_t)(row + j) * N + col] = v;
        } else {
          const int rb = (row + j) >> 8, s = (row + j) & 255;
          const int hh = col >> 6, d = col & 63;
          ((__hip_bfloat16*)Cv)[(((size_t)(rb * 16 + hh) * 64 + d) << 8) + s] =
              __float2bfloat16(v);
        }
      }
    }
  }
}

// 256x256 tile, BK=32, 8 waves, 4-buffer LDS pipeline (128KB), counted vmcnt
// (round-9 structure, proven). outmode: 0 = bf16 row-major, 2 = V^T layout.
__device__ __forceinline__ void gemm256_body(
    const __hip_bfloat16* __restrict__ Abf, const __hip_bfloat16* __restrict__ Wbf,
    const float* __restrict__ bias, __hip_bfloat16* __restrict__ C,
    int N, int K, int outmode, int relu, int bx, int by) {
  __shared__ __align__(16) __hip_bfloat16 AsB[4][256 * 32];  // 4 x 16KB
  __shared__ __align__(16) __hip_bfloat16 BsB[4][256 * 32];  // 4 x 16KB
  const int t = threadIdx.x;           // 0..511
  const int w = t >> 6, lane = t & 63;
  const int lr = lane & 15, lg = lane >> 4;
  const int m0 = bx * 256, n0 = by * 256;
  const int wr = (w >> 2) * 128, wc = (w & 3) * 64;  // per-wave 128x64 output

  const char* Ag = (const char*)Abf;
  const char* Wg = (const char*)Wbf;
  const size_t ldb = (size_t)K * 2;

  f32x4 acc[8][4] = {};

  const int o0 = (w << 10) + lane * 16;
  const int o1 = o0 + 8192;
  const int r0 = o0 >> 6, c0 = o0 & 63;
  const int r1 = o1 >> 6, c1 = o1 & 63;
  const int db0 = (w << 10);
  const int db1 = 8192 + (w << 10);

  auto STAGE = [&](int buf, int tile) {
    const int kt = tile << 5;
    gload_lds16(Ag + (size_t)(m0 + r0) * ldb + kt * 2 + c0, (char*)AsB[buf] + db0);
    gload_lds16(Ag + (size_t)(m0 + r1) * ldb + kt * 2 + c1, (char*)AsB[buf] + db1);
    gload_lds16(Wg + (size_t)(n0 + r0) * ldb + kt * 2 + c0, (char*)BsB[buf] + db0);
    gload_lds16(Wg + (size_t)(n0 + r1) * ldb + kt * 2 + c1, (char*)BsB[buf] + db1);
  };
  auto COMPUTE = [&](int buf) {
    bf16x8 af[8], bfv[4];
#pragma unroll
    for (int mi = 0; mi < 8; ++mi)
      af[mi] = *(const bf16x8*)((const char*)AsB[buf] + ((wr + mi * 16 + lr) << 6) + (lg << 4));
#pragma unroll
    for (int ni = 0; ni < 4; ++ni)
      bfv[ni] = *(const bf16x8*)((const char*)BsB[buf] + ((wc + ni * 16 + lr) << 6) + (lg << 4));
#pragma unroll
    for (int mi = 0; mi < 8; ++mi)
#pragma unroll
      for (int ni = 0; ni < 4; ++ni)
        acc[mi][ni] = MFMA16(af[mi], bfv[ni], acc[mi][ni]);
  };

  const int nt = K >> 5;  // 16 or 24 (>= 4)
  STAGE(0, 0);
  STAGE(1, 1);
  STAGE(2, 2);
  for (int j = 0; j < nt - 3; ++j) {
    STAGE((j + 3) & 3, j + 3);
    asm volatile("s_waitcnt vmcnt(12)" ::: "memory");
    __builtin_amdgcn_s_barrier();
    COMPUTE(j & 3);
    __builtin_amdgcn_s_barrier();
  }
  asm volatile("s_waitcnt vmcnt(8)" ::: "memory");
  __builtin_amdgcn_s_barrier();
  COMPUTE((nt - 3) & 3);
  __builtin_amdgcn_s_barrier();
  asm volatile("s_waitcnt vmcnt(4)" ::: "memory");
  __builtin_amdgcn_s_barrier();
  COMPUTE((nt - 2) & 3);
  __builtin_amdgcn_s_barrier();
  asm volatile("s_waitcnt vmcnt(0)" ::: "memory");
  __builtin_amdgcn_s_barrier();
  COMPUTE((nt - 1) & 3);

#pragma unroll
  for (int ni = 0; ni < 4; ++ni) {
    const int col = n0 + wc + ni * 16 + lr;
    const float bv = bias[col];
#pragma unroll
    for (int mi = 0; mi < 8; ++mi) {
      const int row = m0 + wr + mi * 16 + lg * 4;
#pragma unroll
      for (int j = 0; j < 4; ++j) {
        float v = acc[mi][ni][j] + bv;
        if (relu) v = fmaxf(v, 0.0f);
        if (outmode == 0) {
          C[(size_t)(row + j) * N + col] = __float2bfloat16(v);
        } else {
          const int rb = (row + j) >> 8, s = (row + j) & 255;
          const int hh = col >> 6, d = col & 63;
          C[(((size_t)(rb * 16 + hh) * 64 + d) << 8) + s] = __float2bfloat16(v);
        }
      }
    }
  }
}

// Q, K, V projections in ONE launch: 288 blocks. KV blocks FIRST (0..31) so
// they co-run with Q's 256 blocks instead of serializing after.
__global__ __launch_bounds__(512, 2) void gemm256_qkv(
    const __hip_bfloat16* __restrict__ xb, const __hip_bfloat16* __restrict__ ctxb,
    const __hip_bfloat16* __restrict__ Wq, const __hip_bfloat16* __restrict__ Wk,
    const __hip_bfloat16* __restrict__ Wv,
    const float* __restrict__ bq, const float* __restrict__ bk, const float* __restrict__ bv,
    __hip_bfloat16* __restrict__ Q, __hip_bfloat16* __restrict__ Kp,
    __hip_bfloat16* __restrict__ Vt) {
  const int bid = blockIdx.x;
  if (bid < 16) {        // K-proj: M=1024 N=1024 K=768, grid 4x4
    gemm256_body(ctxb, Wk, bk, Kp, 1024, 768, 0, 0, bid >> 2, bid & 3);
  } else if (bid < 32) { // V-proj (V^T out)
    const int l = bid - 16;
    gemm256_body(ctxb, Wv, bv, Vt, 1024, 768, 2, 0, l >> 2, l & 3);
  } else {               // Q-proj: M=16384 N=1024 K=512, grid 64x4
    const int l = bid - 32;
    gemm256_body(xb, Wq, bq, Q, 1024, 512, 0, 0, l >> 2, l & 3);
  }
}

// P1 (ReLU) on the same pipelined body.
__global__ __launch_bounds__(512, 2) void gemm256_p1(
    const __hip_bfloat16* __restrict__ A, const __hip_bfloat16* __restrict__ W,
    const float* __restrict__ bias, __hip_bfloat16* __restrict__ C) {
  const int bid = blockIdx.x;  // 256 blocks: 64x4
  gemm256_body(A, W, bias, C, 1024, 1024, 0, 1, bid >> 2, bid & 3);
}

// Fused cross-attention: round-7 inner loop, now 8 waves/block (512 thr,
// 128 q-rows) sharing one K/V LDS tile -> 16 resident waves/CU (2x TLP).
__global__ __launch_bounds__(512, 4) void attn_fused(
    const __hip_bfloat16* __restrict__ Qb, const __hip_bfloat16* __restrict__ Kb,
    const __hip_bfloat16* __restrict__ Vtg, const float* __restrict__ padm,
    const float* __restrict__ seqm, __hip_bfloat16* __restrict__ O) {
  constexpr int S = 256, E = 1024, Nq = 4096;
  constexpr float NEGV = -1e9f;
  __shared__ __align__(16) char smem[65536];
  char* VtB = smem;
  char* KsB = smem + 32768;

  const int t = threadIdx.x;           // 0..511
  const int w = t >> 6, lane = t & 63; // 8 waves
  const int lr = lane & 15, lg = lane >> 4;
  const int h = blockIdx.y, b = blockIdx.z;

  // --- stage K [256s][64d]: 4 passes x 512 thr x 16B ---
  const char* Kg = (const char*)(Kb + (size_t)b * S * E + h * 64);
#pragma unroll
  for (int i = 0; i < 4; ++i) {
    const int o = ((i * 8 + w) << 10) + lane * 16;
    const int s = o >> 7, bc = o & 127;
    gload_lds16(Kg + (size_t)s * (E * 2) + (bc ^ ((s & 7) << 4)), KsB + ((i * 8 + w) << 10));
  }
  // --- stage V^T [64d][256s] ---
  const char* Vg = (const char*)Vtg + ((size_t)(b * 16 + h) << 15);
#pragma unroll
  for (int i = 0; i < 4; ++i) {
    const int o = ((i * 8 + w) << 10) + lane * 16;
    const int d = o >> 9, c = o & 511;
    gload_lds16(Vg + (d << 9) + (c ^ ((d & 7) << 4)), VtB + ((i * 8 + w) << 10));
  }

  const int qw = blockIdx.x * 128 + w * 16;
  const short* Qg = (const short*)Qb + (size_t)(b * Nq + qw + lr) * E + h * 64;
  const bf16x8 aq0 = *(const bf16x8*)(Qg + (lg << 3));
  const bf16x8 aq1 = *(const bf16x8*)(Qg + 32 + (lg << 3));
  const float padq = padm[(size_t)b * Nq + qw + lr];
  const float qbias = (padq != 0.f) ? 0.f : NEGV;

  __syncthreads();

  const int swz = (lr & 7) << 4;
  f32x4 o[4] = {};
  float ssum = 0.f;
#pragma unroll
  for (int ni = 0; ni < 16; ++ni) {
    const int s = ni * 16 + lr;
    const bf16x8 bk0 = *(const bf16x8*)(KsB + (s << 7) + ((lg << 4) ^ swz));
    const bf16x8 bk1 = *(const bf16x8*)(KsB + (s << 7) + ((64 + (lg << 4)) ^ swz));
    f32x4 a = {};
    a = MFMA16(bk0, aq0, a);
    a = MFMA16(bk1, aq1, a);

    const float4 sm4 = *(const float4*)(seqm + (size_t)b * S + ni * 16 + lg * 4);
    const float e0 = __expf(a[0] * 0.125f + ((sm4.x != 0.f ? 0.f : NEGV) + qbias));
    const float e1 = __expf(a[1] * 0.125f + ((sm4.y != 0.f ? 0.f : NEGV) + qbias));
    const float e2 = __expf(a[2] * 0.125f + ((sm4.z != 0.f ? 0.f : NEGV) + qbias));
    const float e3 = __expf(a[3] * 0.125f + ((sm4.w != 0.f ? 0.f : NEGV) + qbias));
    ssum += (e0 + e1) + (e2 + e3);

    s16x4 pf;
    __hip_bfloat16 hh;
    hh = __float2bfloat16(e0); pf[0] = *(short*)&hh;
    hh = __float2bfloat16(e1); pf[1] = *(short*)&hh;
    hh = __float2bfloat16(e2); pf[2] = *(short*)&hh;
    hh = __float2bfloat16(e3); pf[3] = *(short*)&hh;

    const int sb = (ni * 32 + lg * 8);
#pragma unroll
    for (int nd = 0; nd < 4; ++nd) {
      const int d = nd * 16 + lr;
      const s16x4 bv = *(const s16x4*)(VtB + (d << 9) + (sb ^ swz));
      o[nd] = MFMAH(pf, bv, o[nd]);
    }
  }

  ssum += __shfl_xor(ssum, 16);
  ssum += __shfl_xor(ssum, 32);
  const float inv = 1.0f / ssum;
  float invj[4];
#pragma unroll
  for (int j = 0; j < 4; ++j) invj[j] = __shfl(inv, lg * 4 + j);

  __hip_bfloat16* Og = O + (size_t)(b * Nq + qw) * E + h * 64;
#pragma unroll
  for (int nd = 0; nd < 4; ++nd)
#pragma unroll
    for (int j = 0; j < 4; ++j)
      Og[(size_t)(lg * 4 + j) * E + nd * 16 + lr] = __float2bfloat16(o[nd][j] * invj[j]);
}

extern "C" void kernel_launch(void* const* d_in, const int* in_sizes, int n_in,
                              void* d_out, int out_size, void* d_ws, size_t ws_size,
                              hipStream_t stream) {
  const float* x    = (const float*)d_in[0];
  const float* ctx  = (const float*)d_in[1];
  const float* padm = (const float*)d_in[2];
  const float* seqm = (const float*)d_in[3];
  const float* Wq_w = (const float*)d_in[4];
  const float* Wq_b = (const float*)d_in[5];
  const float* Wk_w = (const float*)d_in[6];
  const float* Wk_b = (const float*)d_in[7];
  const float* Wv_w = (const float*)d_in[8];
  const float* Wv_b = (const float*)d_in[9];
  const float* P1_w = (const float*)d_in[10];
  const float* P1_b = (const float*)d_in[11];
  const float* P2_w = (const float*)d_in[12];
  const float* P2_b = (const float*)d_in[13];
  float* out = (float*)d_out;

  char* ws = (char*)d_ws;
  size_t off = 0;
  auto alloc = [&](size_t bytes) { char* p = ws + off; off += (bytes + 255) & ~(size_t)255; return p; };
  __hip_bfloat16* Q    = (__hip_bfloat16*)alloc(16384ull * 1024 * 2);  // 32MB (later O1)
  __hip_bfloat16* AO   = (__hip_bfloat16*)alloc(16384ull * 1024 * 2);  // 32MB
  __hip_bfloat16* xb   = (__hip_bfloat16*)alloc(16384ull * 512 * 2);   // 16MB
  __hip_bfloat16* ctxb = (__hip_bfloat16*)alloc(1024ull * 768 * 2);
  __hip_bfloat16* Kp   = (__hip_bfloat16*)alloc(1024ull * 1024 * 2);
  __hip_bfloat16* Vt   = (__hip_bfloat16*)alloc(1024ull * 1024 * 2);   // V^T [b,h][d][s]
  __hip_bfloat16* Wqb  = (__hip_bfloat16*)alloc(1024ull * 512 * 2);
  __hip_bfloat16* Wkb  = (__hip_bfloat16*)alloc(1024ull * 768 * 2);
  __hip_bfloat16* Wvb  = (__hip_bfloat16*)alloc(1024ull * 768 * 2);
  __hip_bfloat16* P1b  = (__hip_bfloat16*)alloc(1024ull * 1024 * 2);
  __hip_bfloat16* P2b  = (__hip_bfloat16*)alloc(512ull * 1024 * 2);
  __hip_bfloat16* O1   = Q;  // reuse Q after attention

  cvt_all<<<dim3(2048, 1, 1), dim3(256, 1, 1), 0, stream>>>(
      x, ctx, Wq_w, Wk_w, Wv_w, P1_w, P2_w, xb, ctxb, Wqb, Wkb, Wvb, P1b, P2b);

  gemm256_qkv<<<dim3(288, 1, 1), dim3(512, 1, 1), 0, stream>>>(
      xb, ctxb, Wqb, Wkb, Wvb, Wq_b, Wk_b, Wv_b, Q, Kp, Vt);
  attn_fused<<<dim3(32, 16, 4), dim3(512, 1, 1), 0, stream>>>(Q, Kp, Vt, padm, seqm, AO);
  gemm256_p1<<<dim3(256, 1, 1), dim3(512, 1, 1), 0, stream>>>(AO, P1b, P1_b, O1);
  gemm_bt<0, 1><<<dim3(128, 4, 1), dim3(256, 1, 1), 0, stream>>>(O1, P2b, P2_b, out, 16384, 512, 1024);
}

// Round 11
// 172.304 us; speedup vs baseline: 1.2282x; 1.0025x over previous
//
#include <hip/hip_runtime.h>
#include <hip/hip_bf16.h>
#include <stdint.h>

typedef __attribute__((ext_vector_type(8))) short bf16x8;   // 8 bf16 (4 VGPRs)
typedef __attribute__((ext_vector_type(4))) short s16x4;
typedef __attribute__((ext_vector_type(4))) float f32x4;

#define MFMA16(a, b, c) __builtin_amdgcn_mfma_f32_16x16x32_bf16((a), (b), (c), 0, 0, 0)
// v_mfma_f32_16x16x16_bf16 — ROCm builtin keeps the gfx90a "_1k" name.
#define MFMAH(a, b, c) __builtin_amdgcn_mfma_f32_16x16x16bf16_1k((a), (b), (c), 0, 0, 0)

__device__ __forceinline__ void gload_lds16(const void* g, void* l) {
  // async global->LDS; HW adds lane*16 to the wave-uniform LDS base
  __builtin_amdgcn_global_load_lds((const __attribute__((address_space(1))) void*)g,
                                   (__attribute__((address_space(3))) void*)l, 16, 0, 0);
}

// ---- all f32->bf16 conversions fused into one grid-stride kernel ----
__global__ void cvt_all(const float* __restrict__ s0, const float* __restrict__ s1,
                        const float* __restrict__ s2, const float* __restrict__ s3,
                        const float* __restrict__ s4, const float* __restrict__ s5,
                        const float* __restrict__ s6,
                        __hip_bfloat16* __restrict__ d0, __hip_bfloat16* __restrict__ d1,
                        __hip_bfloat16* __restrict__ d2, __hip_bfloat16* __restrict__ d3,
                        __hip_bfloat16* __restrict__ d4, __hip_bfloat16* __restrict__ d5,
                        __hip_bfloat16* __restrict__ d6) {
  constexpr int e0 = 2097152;
  constexpr int e1 = e0 + 196608;
  constexpr int e2 = e1 + 131072;
  constexpr int e3 = e2 + 196608;
  constexpr int e4 = e3 + 196608;
  constexpr int e5 = e4 + 262144;
  constexpr int e6 = e5 + 131072;
  const int stride = gridDim.x * blockDim.x;
  for (int i = blockIdx.x * blockDim.x + threadIdx.x; i < e6; i += stride) {
    const float* s; __hip_bfloat16* d; int j;
    if (i < e0)      { s = s0; d = d0; j = i; }
    else if (i < e1) { s = s1; d = d1; j = i - e0; }
    else if (i < e2) { s = s2; d = d2; j = i - e1; }
    else if (i < e3) { s = s3; d = d3; j = i - e2; }
    else if (i < e4) { s = s4; d = d4; j = i - e3; }
    else if (i < e5) { s = s5; d = d5; j = i - e4; }
    else             { s = s6; d = d6; j = i - e5; }
    const float4 v = *(const float4*)(s + (size_t)j * 4);
    s16x4 o;
    __hip_bfloat16 h;
    h = __float2bfloat16(v.x); o[0] = *(short*)&h;
    h = __float2bfloat16(v.y); o[1] = *(short*)&h;
    h = __float2bfloat16(v.z); o[2] = *(short*)&h;
    h = __float2bfloat16(v.w); o[3] = *(short*)&h;
    *(s16x4*)((short*)d + (size_t)j * 4) = o;
  }
}

// LDS slot swizzle for 64B-row GEMM tiles (BK=32): LDS[row][slot] holds global
// chunk slot^((row>>1)&3). Read slot for chunk lg: lg^((lr>>1)&3) (involution).
// Bank math: read group = (4*lr + lg^((lr>>1)&3))%8 -> lr=0..7 hit all 8
// groups, lr=8..15 repeat -> 2-way (free) instead of 8-way.

// C[M,N] = A[M,K] @ W[N,K]^T + bias. 128x128 tile, BK=32, 4 waves (m97 frame).
// OUTMODE: 0 = bf16 row-major; 1 = f32 row-major; 2 = bf16 V^T layout.
template <int RELU, int OUTMODE>
__global__ __launch_bounds__(256, 2) void gemm_bt(
    const __hip_bfloat16* __restrict__ Abf, const __hip_bfloat16* __restrict__ Wbf,
    const float* __restrict__ bias, void* __restrict__ Cv,
    int M, int N, int K) {
  __shared__ __align__(16) __hip_bfloat16 As[128 * 32];
  __shared__ __align__(16) __hip_bfloat16 Bs[128 * 32];
  const int t = threadIdx.x;
  const int w = t >> 6, lane = t & 63;
  const int lr = lane & 15, lg = lane >> 4;
  const int m0 = blockIdx.x * 128, n0 = blockIdx.y * 128;
  const int wr = (w >> 1) * 64, wc = (w & 1) * 64;

  const char* Ag = (const char*)Abf;
  const char* Wg = (const char*)Wbf;
  const size_t ldb = (size_t)K * 2;

  f32x4 acc[4][4] = {};

  const int o0 = (w << 10) + lane * 16;
  const int o1 = o0 + 4096;
  const int r0 = o0 >> 6, gc0 = ((((o0 >> 4) & 3) ^ ((r0 >> 1) & 3)) << 4);
  const int r1 = o1 >> 6, gc1 = ((((o1 >> 4) & 3) ^ ((r1 >> 1) & 3)) << 4);
  const int slx = (lg ^ ((lr >> 1) & 3)) << 4;  // swizzled read slot

  for (int kt = 0; kt < K; kt += 32) {
    if (kt) __syncthreads();
    gload_lds16(Ag + (size_t)(m0 + r0) * ldb + kt * 2 + gc0, (char*)As + (w << 10));
    gload_lds16(Ag + (size_t)(m0 + r1) * ldb + kt * 2 + gc1, (char*)As + 4096 + (w << 10));
    gload_lds16(Wg + (size_t)(n0 + r0) * ldb + kt * 2 + gc0, (char*)Bs + (w << 10));
    gload_lds16(Wg + (size_t)(n0 + r1) * ldb + kt * 2 + gc1, (char*)Bs + 4096 + (w << 10));
    __syncthreads();

    bf16x8 af[4], bfv[4];
#pragma unroll
    for (int mi = 0; mi < 4; ++mi)
      af[mi] = *(const bf16x8*)((const char*)As + ((wr + mi * 16 + lr) << 6) + slx);
#pragma unroll
    for (int ni = 0; ni < 4; ++ni)
      bfv[ni] = *(const bf16x8*)((const char*)Bs + ((wc + ni * 16 + lr) << 6) + slx);
#pragma unroll
    for (int mi = 0; mi < 4; ++mi)
#pragma unroll
      for (int ni = 0; ni < 4; ++ni)
        acc[mi][ni] = MFMA16(af[mi], bfv[ni], acc[mi][ni]);
  }

#pragma unroll
  for (int ni = 0; ni < 4; ++ni) {
    const int col = n0 + wc + ni * 16 + lr;
    const float bv = bias[col];
#pragma unroll
    for (int mi = 0; mi < 4; ++mi) {
      const int row = m0 + wr + mi * 16 + lg * 4;
#pragma unroll
      for (int j = 0; j < 4; ++j) {
        float v = acc[mi][ni][j] + bv;
        if (RELU) v = fmaxf(v, 0.0f);
        if (OUTMODE == 0) {
          ((__hip_bfloat16*)Cv)[(size_t)(row + j) * N + col] = __float2bfloat16(v);
        } else if (OUTMODE == 1) {
          ((float*)Cv)[(size_t)(row + j) * N + col] = v;
        } else {
          const int rb = (row + j) >> 8, s = (row + j) & 255;
          const int hh = col >> 6, d = col & 63;
          ((__hip_bfloat16*)Cv)[(((size_t)(rb * 16 + hh) * 64 + d) << 8) + s] =
              __float2bfloat16(v);
        }
      }
    }
  }
}

// 256x256 tile, BK=32, 8 waves, 4-buffer LDS pipeline (128KB), counted vmcnt,
// slot-XOR swizzled LDS. outmode: 0 = bf16 row-major, 2 = V^T layout.
__device__ __forceinline__ void gemm256_body(
    const __hip_bfloat16* __restrict__ Abf, const __hip_bfloat16* __restrict__ Wbf,
    const float* __restrict__ bias, __hip_bfloat16* __restrict__ C,
    int N, int K, int outmode, int relu, int bx, int by) {
  __shared__ __align__(16) __hip_bfloat16 AsB[4][256 * 32];  // 4 x 16KB
  __shared__ __align__(16) __hip_bfloat16 BsB[4][256 * 32];  // 4 x 16KB
  const int t = threadIdx.x;           // 0..511
  const int w = t >> 6, lane = t & 63;
  const int lr = lane & 15, lg = lane >> 4;
  const int m0 = bx * 256, n0 = by * 256;
  const int wr = (w >> 2) * 128, wc = (w & 3) * 64;  // per-wave 128x64 output

  const char* Ag = (const char*)Abf;
  const char* Wg = (const char*)Wbf;
  const size_t ldb = (size_t)K * 2;

  f32x4 acc[8][4] = {};

  const int o0 = (w << 10) + lane * 16;
  const int o1 = o0 + 8192;
  const int r0 = o0 >> 6, gc0 = ((((o0 >> 4) & 3) ^ ((r0 >> 1) & 3)) << 4);
  const int r1 = o1 >> 6, gc1 = ((((o1 >> 4) & 3) ^ ((r1 >> 1) & 3)) << 4);
  const int slx = (lg ^ ((lr >> 1) & 3)) << 4;  // swizzled read slot
  const int db0 = (w << 10);
  const int db1 = 8192 + (w << 10);

  auto STAGE = [&](int buf, int tile) {
    const int kt = tile << 5;
    gload_lds16(Ag + (size_t)(m0 + r0) * ldb + kt * 2 + gc0, (char*)AsB[buf] + db0);
    gload_lds16(Ag + (size_t)(m0 + r1) * ldb + kt * 2 + gc1, (char*)AsB[buf] + db1);
    gload_lds16(Wg + (size_t)(n0 + r0) * ldb + kt * 2 + gc0, (char*)BsB[buf] + db0);
    gload_lds16(Wg + (size_t)(n0 + r1) * ldb + kt * 2 + gc1, (char*)BsB[buf] + db1);
  };
  auto COMPUTE = [&](int buf) {
    bf16x8 af[8], bfv[4];
#pragma unroll
    for (int mi = 0; mi < 8; ++mi)
      af[mi] = *(const bf16x8*)((const char*)AsB[buf] + ((wr + mi * 16 + lr) << 6) + slx);
#pragma unroll
    for (int ni = 0; ni < 4; ++ni)
      bfv[ni] = *(const bf16x8*)((const char*)BsB[buf] + ((wc + ni * 16 + lr) << 6) + slx);
#pragma unroll
    for (int mi = 0; mi < 8; ++mi)
#pragma unroll
      for (int ni = 0; ni < 4; ++ni)
        acc[mi][ni] = MFMA16(af[mi], bfv[ni], acc[mi][ni]);
  };

  const int nt = K >> 5;  // 16 or 24 (>= 4)
  STAGE(0, 0);
  STAGE(1, 1);
  STAGE(2, 2);
  for (int j = 0; j < nt - 3; ++j) {
    STAGE((j + 3) & 3, j + 3);
    asm volatile("s_waitcnt vmcnt(12)" ::: "memory");
    __builtin_amdgcn_s_barrier();
    COMPUTE(j & 3);
    __builtin_amdgcn_s_barrier();
  }
  asm volatile("s_waitcnt vmcnt(8)" ::: "memory");
  __builtin_amdgcn_s_barrier();
  COMPUTE((nt - 3) & 3);
  __builtin_amdgcn_s_barrier();
  asm volatile("s_waitcnt vmcnt(4)" ::: "memory");
  __builtin_amdgcn_s_barrier();
  COMPUTE((nt - 2) & 3);
  __builtin_amdgcn_s_barrier();
  asm volatile("s_waitcnt vmcnt(0)" ::: "memory");
  __builtin_amdgcn_s_barrier();
  COMPUTE((nt - 1) & 3);

#pragma unroll
  for (int ni = 0; ni < 4; ++ni) {
    const int col = n0 + wc + ni * 16 + lr;
    const float bv = bias[col];
#pragma unroll
    for (int mi = 0; mi < 8; ++mi) {
      const int row = m0 + wr + mi * 16 + lg * 4;
#pragma unroll
      for (int j = 0; j < 4; ++j) {
        float v = acc[mi][ni][j] + bv;
        if (relu) v = fmaxf(v, 0.0f);
        if (outmode == 0) {
          C[(size_t)(row + j) * N + col] = __float2bfloat16(v);
        } else {
          const int rb = (row + j) >> 8, s = (row + j) & 255;
          const int hh = col >> 6, d = col & 63;
          C[(((size_t)(rb * 16 + hh) * 64 + d) << 8) + s] = __float2bfloat16(v);
        }
      }
    }
  }
}

// Q, K, V projections in ONE launch: 288 blocks, KV blocks first.
__global__ __launch_bounds__(512, 2) void gemm256_qkv(
    const __hip_bfloat16* __restrict__ xb, const __hip_bfloat16* __restrict__ ctxb,
    const __hip_bfloat16* __restrict__ Wq, const __hip_bfloat16* __restrict__ Wk,
    const __hip_bfloat16* __restrict__ Wv,
    const float* __restrict__ bq, const float* __restrict__ bk, const float* __restrict__ bv,
    __hip_bfloat16* __restrict__ Q, __hip_bfloat16* __restrict__ Kp,
    __hip_bfloat16* __restrict__ Vt) {
  const int bid = blockIdx.x;
  if (bid < 16) {
    gemm256_body(ctxb, Wk, bk, Kp, 1024, 768, 0, 0, bid >> 2, bid & 3);
  } else if (bid < 32) {
    const int l = bid - 16;
    gemm256_body(ctxb, Wv, bv, Vt, 1024, 768, 2, 0, l >> 2, l & 3);
  } else {
    const int l = bid - 32;
    gemm256_body(xb, Wq, bq, Q, 1024, 512, 0, 0, l >> 2, l & 3);
  }
}

// P1 (ReLU) on the same pipelined body.
__global__ __launch_bounds__(512, 2) void gemm256_p1(
    const __hip_bfloat16* __restrict__ A, const __hip_bfloat16* __restrict__ W,
    const float* __restrict__ bias, __hip_bfloat16* __restrict__ C) {
  const int bid = blockIdx.x;  // 256 blocks: 64x4
  gemm256_body(A, W, bias, C, 1024, 1024, 0, 1, bid >> 2, bid & 3);
}

// Fused cross-attention (round-10, frozen): 8 waves/block, swapped QK^T,
// register P, 16x16x16 PV.
__global__ __launch_bounds__(512, 4) void attn_fused(
    const __hip_bfloat16* __restrict__ Qb, const __hip_bfloat16* __restrict__ Kb,
    const __hip_bfloat16* __restrict__ Vtg, const float* __restrict__ padm,
    const float* __restrict__ seqm, __hip_bfloat16* __restrict__ O) {
  constexpr int S = 256, E = 1024, Nq = 4096;
  constexpr float NEGV = -1e9f;
  __shared__ __align__(16) char smem[65536];
  char* VtB = smem;
  char* KsB = smem + 32768;

  const int t = threadIdx.x;           // 0..511
  const int w = t >> 6, lane = t & 63; // 8 waves
  const int lr = lane & 15, lg = lane >> 4;
  const int h = blockIdx.y, b = blockIdx.z;

  const char* Kg = (const char*)(Kb + (size_t)b * S * E + h * 64);
#pragma unroll
  for (int i = 0; i < 4; ++i) {
    const int o = ((i * 8 + w) << 10) + lane * 16;
    const int s = o >> 7, bc = o & 127;
    gload_lds16(Kg + (size_t)s * (E * 2) + (bc ^ ((s & 7) << 4)), KsB + ((i * 8 + w) << 10));
  }
  const char* Vg = (const char*)Vtg + ((size_t)(b * 16 + h) << 15);
#pragma unroll
  for (int i = 0; i < 4; ++i) {
    const int o = ((i * 8 + w) << 10) + lane * 16;
    const int d = o >> 9, c = o & 511;
    gload_lds16(Vg + (d << 9) + (c ^ ((d & 7) << 4)), VtB + ((i * 8 + w) << 10));
  }

  const int qw = blockIdx.x * 128 + w * 16;
  const short* Qg = (const short*)Qb + (size_t)(b * Nq + qw + lr) * E + h * 64;
  const bf16x8 aq0 = *(const bf16x8*)(Qg + (lg << 3));
  const bf16x8 aq1 = *(const bf16x8*)(Qg + 32 + (lg << 3));
  const float padq = padm[(size_t)b * Nq + qw + lr];
  const float qbias = (padq != 0.f) ? 0.f : NEGV;

  __syncthreads();

  const int swz = (lr & 7) << 4;
  f32x4 o[4] = {};
  float ssum = 0.f;
#pragma unroll
  for (int ni = 0; ni < 16; ++ni) {
    const int s = ni * 16 + lr;
    const bf16x8 bk0 = *(const bf16x8*)(KsB + (s << 7) + ((lg << 4) ^ swz));
    const bf16x8 bk1 = *(const bf16x8*)(KsB + (s << 7) + ((64 + (lg << 4)) ^ swz));
    f32x4 a = {};
    a = MFMA16(bk0, aq0, a);
    a = MFMA16(bk1, aq1, a);

    const float4 sm4 = *(const float4*)(seqm + (size_t)b * S + ni * 16 + lg * 4);
    const float e0 = __expf(a[0] * 0.125f + ((sm4.x != 0.f ? 0.f : NEGV) + qbias));
    const float e1 = __expf(a[1] * 0.125f + ((sm4.y != 0.f ? 0.f : NEGV) + qbias));
    const float e2 = __expf(a[2] * 0.125f + ((sm4.z != 0.f ? 0.f : NEGV) + qbias));
    const float e3 = __expf(a[3] * 0.125f + ((sm4.w != 0.f ? 0.f : NEGV) + qbias));
    ssum += (e0 + e1) + (e2 + e3);

    s16x4 pf;
    __hip_bfloat16 hh;
    hh = __float2bfloat16(e0); pf[0] = *(short*)&hh;
    hh = __float2bfloat16(e1); pf[1] = *(short*)&hh;
    hh = __float2bfloat16(e2); pf[2] = *(short*)&hh;
    hh = __float2bfloat16(e3); pf[3] = *(short*)&hh;

    const int sb = (ni * 32 + lg * 8);
#pragma unroll
    for (int nd = 0; nd < 4; ++nd) {
      const int d = nd * 16 + lr;
      const s16x4 bv = *(const s16x4*)(VtB + (d << 9) + (sb ^ swz));
      o[nd] = MFMAH(pf, bv, o[nd]);
    }
  }

  ssum += __shfl_xor(ssum, 16);
  ssum += __shfl_xor(ssum, 32);
  const float inv = 1.0f / ssum;
  float invj[4];
#pragma unroll
  for (int j = 0; j < 4; ++j) invj[j] = __shfl(inv, lg * 4 + j);

  __hip_bfloat16* Og = O + (size_t)(b * Nq + qw) * E + h * 64;
#pragma unroll
  for (int nd = 0; nd < 4; ++nd)
#pragma unroll
    for (int j = 0; j < 4; ++j)
      Og[(size_t)(lg * 4 + j) * E + nd * 16 + lr] = __float2bfloat16(o[nd][j] * invj[j]);
}

extern "C" void kernel_launch(void* const* d_in, const int* in_sizes, int n_in,
                              void* d_out, int out_size, void* d_ws, size_t ws_size,
                              hipStream_t stream) {
  const float* x    = (const float*)d_in[0];
  const float* ctx  = (const float*)d_in[1];
  const float* padm = (const float*)d_in[2];
  const float* seqm = (const float*)d_in[3];
  const float* Wq_w = (const float*)d_in[4];
  const float* Wq_b = (const float*)d_in[5];
  const float* Wk_w = (const float*)d_in[6];
  const float* Wk_b = (const float*)d_in[7];
  const float* Wv_w = (const float*)d_in[8];
  const float* Wv_b = (const float*)d_in[9];
  const float* P1_w = (const float*)d_in[10];
  const float* P1_b = (const float*)d_in[11];
  const float* P2_w = (const float*)d_in[12];
  const float* P2_b = (const float*)d_in[13];
  float* out = (float*)d_out;

  char* ws = (char*)d_ws;
  size_t off = 0;
  auto alloc = [&](size_t bytes) { char* p = ws + off; off += (bytes + 255) & ~(size_t)255; return p; };
  __hip_bfloat16* Q    = (__hip_bfloat16*)alloc(16384ull * 1024 * 2);  // 32MB (later O1)
  __hip_bfloat16* AO   = (__hip_bfloat16*)alloc(16384ull * 1024 * 2);  // 32MB
  __hip_bfloat16* xb   = (__hip_bfloat16*)alloc(16384ull * 512 * 2);   // 16MB
  __hip_bfloat16* ctxb = (__hip_bfloat16*)alloc(1024ull * 768 * 2);
  __hip_bfloat16* Kp   = (__hip_bfloat16*)alloc(1024ull * 1024 * 2);
  __hip_bfloat16* Vt   = (__hip_bfloat16*)alloc(1024ull * 1024 * 2);   // V^T [b,h][d][s]
  __hip_bfloat16* Wqb  = (__hip_bfloat16*)alloc(1024ull * 512 * 2);
  __hip_bfloat16* Wkb  = (__hip_bfloat16*)alloc(1024ull * 768 * 2);
  __hip_bfloat16* Wvb  = (__hip_bfloat16*)alloc(1024ull * 768 * 2);
  __hip_bfloat16* P1b  = (__hip_bfloat16*)alloc(1024ull * 1024 * 2);
  __hip_bfloat16* P2b  = (__hip_bfloat16*)alloc(512ull * 1024 * 2);
  __hip_bfloat16* O1   = Q;  // reuse Q after attention

  cvt_all<<<dim3(2048, 1, 1), dim3(256, 1, 1), 0, stream>>>(
      x, ctx, Wq_w, Wk_w, Wv_w, P1_w, P2_w, xb, ctxb, Wqb, Wkb, Wvb, P1b, P2b);

  gemm256_qkv<<<dim3(288, 1, 1), dim3(512, 1, 1), 0, stream>>>(
      xb, ctxb, Wqb, Wkb, Wvb, Wq_b, Wk_b, Wv_b, Q, Kp, Vt);
  attn_fused<<<dim3(32, 16, 4), dim3(512, 1, 1), 0, stream>>>(Q, Kp, Vt, padm, seqm, AO);
  gemm256_p1<<<dim3(256, 1, 1), dim3(512, 1, 1), 0, stream>>>(AO, P1b, P1_b, O1);
  gemm_bt<0, 1><<<dim3(128, 4, 1), dim3(256, 1, 1), 0, stream>>>(O1, P2b, P2_b, out, 16384, 512, 1024);
}

// Round 12
// 169.804 us; speedup vs baseline: 1.2462x; 1.0147x over previous
//
#include <hip/hip_runtime.h>
#include <hip/hip_bf16.h>
#include <stdint.h>

typedef __attribute__((ext_vector_type(8))) short bf16x8;   // 8 bf16 (4 VGPRs)
typedef __attribute__((ext_vector_type(4))) short s16x4;
typedef __attribute__((ext_vector_type(4))) float f32x4;

#define MFMA16(a, b, c) __builtin_amdgcn_mfma_f32_16x16x32_bf16((a), (b), (c), 0, 0, 0)
// v_mfma_f32_16x16x16_bf16 — ROCm builtin keeps the gfx90a "_1k" name.
#define MFMAH(a, b, c) __builtin_amdgcn_mfma_f32_16x16x16bf16_1k((a), (b), (c), 0, 0, 0)

__device__ __forceinline__ void gload_lds16(const void* g, void* l) {
  // async global->LDS; HW adds lane*16 to the wave-uniform LDS base
  __builtin_amdgcn_global_load_lds((const __attribute__((address_space(1))) void*)g,
                                   (__attribute__((address_space(3))) void*)l, 16, 0, 0);
}

// ---- all f32->bf16 conversions fused into one grid-stride kernel ----
__global__ void cvt_all(const float* __restrict__ s0, const float* __restrict__ s1,
                        const float* __restrict__ s2, const float* __restrict__ s3,
                        const float* __restrict__ s4, const float* __restrict__ s5,
                        const float* __restrict__ s6,
                        __hip_bfloat16* __restrict__ d0, __hip_bfloat16* __restrict__ d1,
                        __hip_bfloat16* __restrict__ d2, __hip_bfloat16* __restrict__ d3,
                        __hip_bfloat16* __restrict__ d4, __hip_bfloat16* __restrict__ d5,
                        __hip_bfloat16* __restrict__ d6) {
  constexpr int e0 = 2097152;
  constexpr int e1 = e0 + 196608;
  constexpr int e2 = e1 + 131072;
  constexpr int e3 = e2 + 196608;
  constexpr int e4 = e3 + 196608;
  constexpr int e5 = e4 + 262144;
  constexpr int e6 = e5 + 131072;
  const int stride = gridDim.x * blockDim.x;
  for (int i = blockIdx.x * blockDim.x + threadIdx.x; i < e6; i += stride) {
    const float* s; __hip_bfloat16* d; int j;
    if (i < e0)      { s = s0; d = d0; j = i; }
    else if (i < e1) { s = s1; d = d1; j = i - e0; }
    else if (i < e2) { s = s2; d = d2; j = i - e1; }
    else if (i < e3) { s = s3; d = d3; j = i - e2; }
    else if (i < e4) { s = s4; d = d4; j = i - e3; }
    else if (i < e5) { s = s5; d = d5; j = i - e4; }
    else             { s = s6; d = d6; j = i - e5; }
    const float4 v = *(const float4*)(s + (size_t)j * 4);
    s16x4 o;
    __hip_bfloat16 h;
    h = __float2bfloat16(v.x); o[0] = *(short*)&h;
    h = __float2bfloat16(v.y); o[1] = *(short*)&h;
    h = __float2bfloat16(v.z); o[2] = *(short*)&h;
    h = __float2bfloat16(v.w); o[3] = *(short*)&h;
    *(s16x4*)((short*)d + (size_t)j * 4) = o;
  }
}

// LDS slot swizzle (proven: conflicts -> 0): LDS[row][slot] holds global chunk
// slot^((row>>1)&3); read slot for chunk lg: lg^((lr>>1)&3).

// C[M,N] = A[M,K] @ W[N,K]^T + bias. 128x128 tile, BK=32, 4 waves (m97 frame).
// OUTMODE: 0 = bf16 row-major; 1 = f32 row-major; 2 = bf16 V^T layout.
template <int RELU, int OUTMODE>
__global__ __launch_bounds__(256, 2) void gemm_bt(
    const __hip_bfloat16* __restrict__ Abf, const __hip_bfloat16* __restrict__ Wbf,
    const float* __restrict__ bias, void* __restrict__ Cv,
    int M, int N, int K) {
  __shared__ __align__(16) __hip_bfloat16 As[128 * 32];
  __shared__ __align__(16) __hip_bfloat16 Bs[128 * 32];
  const int t = threadIdx.x;
  const int w = t >> 6, lane = t & 63;
  const int lr = lane & 15, lg = lane >> 4;
  const int m0 = blockIdx.x * 128, n0 = blockIdx.y * 128;
  const int wr = (w >> 1) * 64, wc = (w & 1) * 64;

  const char* Ag = (const char*)Abf;
  const char* Wg = (const char*)Wbf;
  const size_t ldb = (size_t)K * 2;

  f32x4 acc[4][4] = {};

  const int o0 = (w << 10) + lane * 16;
  const int o1 = o0 + 4096;
  const int r0 = o0 >> 6, gc0 = ((((o0 >> 4) & 3) ^ ((r0 >> 1) & 3)) << 4);
  const int r1 = o1 >> 6, gc1 = ((((o1 >> 4) & 3) ^ ((r1 >> 1) & 3)) << 4);
  const int slx = (lg ^ ((lr >> 1) & 3)) << 4;

  for (int kt = 0; kt < K; kt += 32) {
    if (kt) __syncthreads();
    gload_lds16(Ag + (size_t)(m0 + r0) * ldb + kt * 2 + gc0, (char*)As + (w << 10));
    gload_lds16(Ag + (size_t)(m0 + r1) * ldb + kt * 2 + gc1, (char*)As + 4096 + (w << 10));
    gload_lds16(Wg + (size_t)(n0 + r0) * ldb + kt * 2 + gc0, (char*)Bs + (w << 10));
    gload_lds16(Wg + (size_t)(n0 + r1) * ldb + kt * 2 + gc1, (char*)Bs + 4096 + (w << 10));
    __syncthreads();

    bf16x8 af[4], bfv[4];
#pragma unroll
    for (int mi = 0; mi < 4; ++mi)
      af[mi] = *(const bf16x8*)((const char*)As + ((wr + mi * 16 + lr) << 6) + slx);
#pragma unroll
    for (int ni = 0; ni < 4; ++ni)
      bfv[ni] = *(const bf16x8*)((const char*)Bs + ((wc + ni * 16 + lr) << 6) + slx);
#pragma unroll
    for (int mi = 0; mi < 4; ++mi)
#pragma unroll
      for (int ni = 0; ni < 4; ++ni)
        acc[mi][ni] = MFMA16(af[mi], bfv[ni], acc[mi][ni]);
  }

#pragma unroll
  for (int ni = 0; ni < 4; ++ni) {
    const int col = n0 + wc + ni * 16 + lr;
    const float bv = bias[col];
#pragma unroll
    for (int mi = 0; mi < 4; ++mi) {
      const int row = m0 + wr + mi * 16 + lg * 4;
#pragma unroll
      for (int j = 0; j < 4; ++j) {
        float v = acc[mi][ni][j] + bv;
        if (RELU) v = fmaxf(v, 0.0f);
        if (OUTMODE == 0) {
          ((__hip_bfloat16*)Cv)[(size_t)(row + j) * N + col] = __float2bfloat16(v);
        } else if (OUTMODE == 1) {
          ((float*)Cv)[(size_t)(row + j) * N + col] = v;
        } else {
          const int rb = (row + j) >> 8, s = (row + j) & 255;
          const int hh = col >> 6, d = col & 63;
          ((__hip_bfloat16*)Cv)[(((size_t)(rb * 16 + hh) * 64 + d) << 8) + s] =
              __float2bfloat16(v);
        }
      }
    }
  }
}

// 256x256 tile, BK=32, 8 waves, 4-buffer pipeline + PHASE-SPLIT schedule (T3):
// per K-tile, 2 phases of {ds_read subtile || 2 gload_lds -> s_barrier ->
// lgkmcnt(0)+sched_barrier -> setprio(1) 16 MFMA setprio(0) -> s_barrier}.
// Counted vmcnt once per K-tile (T4): steady-state outstanding 12, wait
// oldest 4 -> vmcnt(8); tail 4 -> vmcnt(4) -> vmcnt(0).
// Hazard audit: stage of tile j+3 targets buf (j-1)&3, whose reads completed
// before tile j-1's trailing barrier; all barriers wave-uniform.
__device__ __forceinline__ void gemm256_body(
    const __hip_bfloat16* __restrict__ Abf, const __hip_bfloat16* __restrict__ Wbf,
    const float* __restrict__ bias, __hip_bfloat16* __restrict__ C,
    int N, int K, int outmode, int relu, int bx, int by) {
  __shared__ __align__(16) __hip_bfloat16 AsB[4][256 * 32];  // 4 x 16KB
  __shared__ __align__(16) __hip_bfloat16 BsB[4][256 * 32];  // 4 x 16KB
  const int t = threadIdx.x;           // 0..511
  const int w = t >> 6, lane = t & 63;
  const int lr = lane & 15, lg = lane >> 4;
  const int m0 = bx * 256, n0 = by * 256;
  const int wr = (w >> 2) * 128, wc = (w & 3) * 64;  // per-wave 128x64 output

  const char* Ag = (const char*)Abf;
  const char* Wg = (const char*)Wbf;
  const size_t ldb = (size_t)K * 2;

  f32x4 acc[8][4] = {};

  const int o0 = (w << 10) + lane * 16;
  const int o1 = o0 + 8192;
  const int r0 = o0 >> 6, gc0 = ((((o0 >> 4) & 3) ^ ((r0 >> 1) & 3)) << 4);
  const int r1 = o1 >> 6, gc1 = ((((o1 >> 4) & 3) ^ ((r1 >> 1) & 3)) << 4);
  const int slx = (lg ^ ((lr >> 1) & 3)) << 4;
  const int db0 = (w << 10);
  const int db1 = 8192 + (w << 10);

  auto STAGE_A = [&](int buf, int tile) {
    const int kt = tile << 5;
    gload_lds16(Ag + (size_t)(m0 + r0) * ldb + kt * 2 + gc0, (char*)AsB[buf] + db0);
    gload_lds16(Ag + (size_t)(m0 + r1) * ldb + kt * 2 + gc1, (char*)AsB[buf] + db1);
  };
  auto STAGE_B = [&](int buf, int tile) {
    const int kt = tile << 5;
    gload_lds16(Wg + (size_t)(n0 + r0) * ldb + kt * 2 + gc0, (char*)BsB[buf] + db0);
    gload_lds16(Wg + (size_t)(n0 + r1) * ldb + kt * 2 + gc1, (char*)BsB[buf] + db1);
  };

  // vmsel: 0 -> vmcnt(8), 1 -> vmcnt(4), 2 -> vmcnt(0), 3 -> none
  auto tile_body = [&](int j, int stage_tile, int vmsel) {
    const int buf = j & 3;
    const int nbuf = stage_tile & 3;
    bf16x8 af0[4], af1[4], bfv[4];
    // ---- phase 0: reads + A-stage -> barrier -> MFMA(mi 0-3) ----
#pragma unroll
    for (int mi = 0; mi < 4; ++mi)
      af0[mi] = *(const bf16x8*)((const char*)AsB[buf] + ((wr + mi * 16 + lr) << 6) + slx);
#pragma unroll
    for (int ni = 0; ni < 4; ++ni)
      bfv[ni] = *(const bf16x8*)((const char*)BsB[buf] + ((wc + ni * 16 + lr) << 6) + slx);
    if (stage_tile >= 0) STAGE_A(nbuf, stage_tile);
    asm volatile("s_barrier" ::: "memory");
    asm volatile("s_waitcnt lgkmcnt(0)" ::: "memory");
    __builtin_amdgcn_sched_barrier(0);
    __builtin_amdgcn_s_setprio(1);
#pragma unroll
    for (int mi = 0; mi < 4; ++mi)
#pragma unroll
      for (int ni = 0; ni < 4; ++ni)
        acc[mi][ni] = MFMA16(af0[mi], bfv[ni], acc[mi][ni]);
    __builtin_amdgcn_s_setprio(0);
    asm volatile("s_barrier" ::: "memory");
    // ---- phase 1: reads + B-stage + vmcnt -> barrier -> MFMA(mi 4-7) ----
#pragma unroll
    for (int mi = 0; mi < 4; ++mi)
      af1[mi] = *(const bf16x8*)((const char*)AsB[buf] + ((wr + (mi + 4) * 16 + lr) << 6) + slx);
    if (stage_tile >= 0) STAGE_B(nbuf, stage_tile);
    if (vmsel == 0)      asm volatile("s_waitcnt vmcnt(8)" ::: "memory");
    else if (vmsel == 1) asm volatile("s_waitcnt vmcnt(4)" ::: "memory");
    else if (vmsel == 2) asm volatile("s_waitcnt vmcnt(0)" ::: "memory");
    asm volatile("s_barrier" ::: "memory");
    asm volatile("s_waitcnt lgkmcnt(0)" ::: "memory");
    __builtin_amdgcn_sched_barrier(0);
    __builtin_amdgcn_s_setprio(1);
#pragma unroll
    for (int mi = 0; mi < 4; ++mi)
#pragma unroll
      for (int ni = 0; ni < 4; ++ni)
        acc[mi + 4][ni] = MFMA16(af1[mi], bfv[ni], acc[mi + 4][ni]);
    __builtin_amdgcn_s_setprio(0);
    asm volatile("s_barrier" ::: "memory");
  };

  const int nt = K >> 5;  // 16/24/32, all >= 4
  STAGE_A(0, 0); STAGE_B(0, 0);
  STAGE_A(1, 1); STAGE_B(1, 1);
  STAGE_A(2, 2); STAGE_B(2, 2);
  asm volatile("s_waitcnt vmcnt(8)" ::: "memory");   // tile 0 landed
  asm volatile("s_barrier" ::: "memory");
  for (int j = 0; j < nt - 3; ++j)
    tile_body(j, j + 3, 0);
  tile_body(nt - 3, -1, 1);
  tile_body(nt - 2, -1, 2);
  tile_body(nt - 1, -1, 3);

#pragma unroll
  for (int ni = 0; ni < 4; ++ni) {
    const int col = n0 + wc + ni * 16 + lr;
    const float bv = bias[col];
#pragma unroll
    for (int mi = 0; mi < 8; ++mi) {
      const int row = m0 + wr + mi * 16 + lg * 4;
#pragma unroll
      for (int j = 0; j < 4; ++j) {
        float v = acc[mi][ni][j] + bv;
        if (relu) v = fmaxf(v, 0.0f);
        if (outmode == 0) {
          C[(size_t)(row + j) * N + col] = __float2bfloat16(v);
        } else {
          const int rb = (row + j) >> 8, s = (row + j) & 255;
          const int hh = col >> 6, d = col & 63;
          C[(((size_t)(rb * 16 + hh) * 64 + d) << 8) + s] = __float2bfloat16(v);
        }
      }
    }
  }
}

// Q, K, V projections in ONE launch: 288 blocks, KV blocks first. Q part uses
// XCD-chunked remap: XCD k (= bid%8, 32|bid-offset) gets bx in [8k,8k+8) ->
// per-XCD A working set 4MB (fits L2) instead of ~16MB.
__global__ __launch_bounds__(512, 2) void gemm256_qkv(
    const __hip_bfloat16* __restrict__ xb, const __hip_bfloat16* __restrict__ ctxb,
    const __hip_bfloat16* __restrict__ Wq, const __hip_bfloat16* __restrict__ Wk,
    const __hip_bfloat16* __restrict__ Wv,
    const float* __restrict__ bq, const float* __restrict__ bk, const float* __restrict__ bv,
    __hip_bfloat16* __restrict__ Q, __hip_bfloat16* __restrict__ Kp,
    __hip_bfloat16* __restrict__ Vt) {
  const int bid = blockIdx.x;
  if (bid < 16) {
    gemm256_body(ctxb, Wk, bk, Kp, 1024, 768, 0, 0, bid >> 2, bid & 3);
  } else if (bid < 32) {
    const int l = bid - 16;
    gemm256_body(ctxb, Wv, bv, Vt, 1024, 768, 2, 0, l >> 2, l & 3);
  } else {
    const int l = bid - 32;                      // l%8 == bid%8 (XCD id)
    const int rb = (l & 7) * 32 + (l >> 3);      // bijective (256 % 8 == 0)
    gemm256_body(xb, Wq, bq, Q, 1024, 512, 0, 0, rb >> 2, rb & 3);
  }
}

// P1 (ReLU), XCD-chunked remap.
__global__ __launch_bounds__(512, 2) void gemm256_p1(
    const __hip_bfloat16* __restrict__ A, const __hip_bfloat16* __restrict__ W,
    const float* __restrict__ bias, __hip_bfloat16* __restrict__ C) {
  const int bid = blockIdx.x;  // 256 blocks
  const int rb = (bid & 7) * 32 + (bid >> 3);
  gemm256_body(A, W, bias, C, 1024, 1024, 0, 1, rb >> 2, rb & 3);
}

// Fused cross-attention (round-10, frozen): 8 waves/block, swapped QK^T,
// register P, 16x16x16 PV.
__global__ __launch_bounds__(512, 4) void attn_fused(
    const __hip_bfloat16* __restrict__ Qb, const __hip_bfloat16* __restrict__ Kb,
    const __hip_bfloat16* __restrict__ Vtg, const float* __restrict__ padm,
    const float* __restrict__ seqm, __hip_bfloat16* __restrict__ O) {
  constexpr int S = 256, E = 1024, Nq = 4096;
  constexpr float NEGV = -1e9f;
  __shared__ __align__(16) char smem[65536];
  char* VtB = smem;
  char* KsB = smem + 32768;

  const int t = threadIdx.x;           // 0..511
  const int w = t >> 6, lane = t & 63; // 8 waves
  const int lr = lane & 15, lg = lane >> 4;
  const int h = blockIdx.y, b = blockIdx.z;

  const char* Kg = (const char*)(Kb + (size_t)b * S * E + h * 64);
#pragma unroll
  for (int i = 0; i < 4; ++i) {
    const int o = ((i * 8 + w) << 10) + lane * 16;
    const int s = o >> 7, bc = o & 127;
    gload_lds16(Kg + (size_t)s * (E * 2) + (bc ^ ((s & 7) << 4)), KsB + ((i * 8 + w) << 10));
  }
  const char* Vg = (const char*)Vtg + ((size_t)(b * 16 + h) << 15);
#pragma unroll
  for (int i = 0; i < 4; ++i) {
    const int o = ((i * 8 + w) << 10) + lane * 16;
    const int d = o >> 9, c = o & 511;
    gload_lds16(Vg + (d << 9) + (c ^ ((d & 7) << 4)), VtB + ((i * 8 + w) << 10));
  }

  const int qw = blockIdx.x * 128 + w * 16;
  const short* Qg = (const short*)Qb + (size_t)(b * Nq + qw + lr) * E + h * 64;
  const bf16x8 aq0 = *(const bf16x8*)(Qg + (lg << 3));
  const bf16x8 aq1 = *(const bf16x8*)(Qg + 32 + (lg << 3));
  const float padq = padm[(size_t)b * Nq + qw + lr];
  const float qbias = (padq != 0.f) ? 0.f : NEGV;

  __syncthreads();

  const int swz = (lr & 7) << 4;
  f32x4 o[4] = {};
  float ssum = 0.f;
#pragma unroll
  for (int ni = 0; ni < 16; ++ni) {
    const int s = ni * 16 + lr;
    const bf16x8 bk0 = *(const bf16x8*)(KsB + (s << 7) + ((lg << 4) ^ swz));
    const bf16x8 bk1 = *(const bf16x8*)(KsB + (s << 7) + ((64 + (lg << 4)) ^ swz));
    f32x4 a = {};
    a = MFMA16(bk0, aq0, a);
    a = MFMA16(bk1, aq1, a);

    const float4 sm4 = *(const float4*)(seqm + (size_t)b * S + ni * 16 + lg * 4);
    const float e0 = __expf(a[0] * 0.125f + ((sm4.x != 0.f ? 0.f : NEGV) + qbias));
    const float e1 = __expf(a[1] * 0.125f + ((sm4.y != 0.f ? 0.f : NEGV) + qbias));
    const float e2 = __expf(a[2] * 0.125f + ((sm4.z != 0.f ? 0.f : NEGV) + qbias));
    const float e3 = __expf(a[3] * 0.125f + ((sm4.w != 0.f ? 0.f : NEGV) + qbias));
    ssum += (e0 + e1) + (e2 + e3);

    s16x4 pf;
    __hip_bfloat16 hh;
    hh = __float2bfloat16(e0); pf[0] = *(short*)&hh;
    hh = __float2bfloat16(e1); pf[1] = *(short*)&hh;
    hh = __float2bfloat16(e2); pf[2] = *(short*)&hh;
    hh = __float2bfloat16(e3); pf[3] = *(short*)&hh;

    const int sb = (ni * 32 + lg * 8);
#pragma unroll
    for (int nd = 0; nd < 4; ++nd) {
      const int d = nd * 16 + lr;
      const s16x4 bv = *(const s16x4*)(VtB + (d << 9) + (sb ^ swz));
      o[nd] = MFMAH(pf, bv, o[nd]);
    }
  }

  ssum += __shfl_xor(ssum, 16);
  ssum += __shfl_xor(ssum, 32);
  const float inv = 1.0f / ssum;
  float invj[4];
#pragma unroll
  for (int j = 0; j < 4; ++j) invj[j] = __shfl(inv, lg * 4 + j);

  __hip_bfloat16* Og = O + (size_t)(b * Nq + qw) * E + h * 64;
#pragma unroll
  for (int nd = 0; nd < 4; ++nd)
#pragma unroll
    for (int j = 0; j < 4; ++j)
      Og[(size_t)(lg * 4 + j) * E + nd * 16 + lr] = __float2bfloat16(o[nd][j] * invj[j]);
}

extern "C" void kernel_launch(void* const* d_in, const int* in_sizes, int n_in,
                              void* d_out, int out_size, void* d_ws, size_t ws_size,
                              hipStream_t stream) {
  const float* x    = (const float*)d_in[0];
  const float* ctx  = (const float*)d_in[1];
  const float* padm = (const float*)d_in[2];
  const float* seqm = (const float*)d_in[3];
  const float* Wq_w = (const float*)d_in[4];
  const float* Wq_b = (const float*)d_in[5];
  const float* Wk_w = (const float*)d_in[6];
  const float* Wk_b = (const float*)d_in[7];
  const float* Wv_w = (const float*)d_in[8];
  const float* Wv_b = (const float*)d_in[9];
  const float* P1_w = (const float*)d_in[10];
  const float* P1_b = (const float*)d_in[11];
  const float* P2_w = (const float*)d_in[12];
  const float* P2_b = (const float*)d_in[13];
  float* out = (float*)d_out;

  char* ws = (char*)d_ws;
  size_t off = 0;
  auto alloc = [&](size_t bytes) { char* p = ws + off; off += (bytes + 255) & ~(size_t)255; return p; };
  __hip_bfloat16* Q    = (__hip_bfloat16*)alloc(16384ull * 1024 * 2);  // 32MB (later O1)
  __hip_bfloat16* AO   = (__hip_bfloat16*)alloc(16384ull * 1024 * 2);  // 32MB
  __hip_bfloat16* xb   = (__hip_bfloat16*)alloc(16384ull * 512 * 2);   // 16MB
  __hip_bfloat16* ctxb = (__hip_bfloat16*)alloc(1024ull * 768 * 2);
  __hip_bfloat16* Kp   = (__hip_bfloat16*)alloc(1024ull * 1024 * 2);
  __hip_bfloat16* Vt   = (__hip_bfloat16*)alloc(1024ull * 1024 * 2);   // V^T [b,h][d][s]
  __hip_bfloat16* Wqb  = (__hip_bfloat16*)alloc(1024ull * 512 * 2);
  __hip_bfloat16* Wkb  = (__hip_bfloat16*)alloc(1024ull * 768 * 2);
  __hip_bfloat16* Wvb  = (__hip_bfloat16*)alloc(1024ull * 768 * 2);
  __hip_bfloat16* P1b  = (__hip_bfloat16*)alloc(1024ull * 1024 * 2);
  __hip_bfloat16* P2b  = (__hip_bfloat16*)alloc(512ull * 1024 * 2);
  __hip_bfloat16* O1   = Q;  // reuse Q after attention

  cvt_all<<<dim3(2048, 1, 1), dim3(256, 1, 1), 0, stream>>>(
      x, ctx, Wq_w, Wk_w, Wv_w, P1_w, P2_w, xb, ctxb, Wqb, Wkb, Wvb, P1b, P2b);

  gemm256_qkv<<<dim3(288, 1, 1), dim3(512, 1, 1), 0, stream>>>(
      xb, ctxb, Wqb, Wkb, Wvb, Wq_b, Wk_b, Wv_b, Q, Kp, Vt);
  attn_fused<<<dim3(32, 16, 4), dim3(512, 1, 1), 0, stream>>>(Q, Kp, Vt, padm, seqm, AO);
  gemm256_p1<<<dim3(256, 1, 1), dim3(512, 1, 1), 0, stream>>>(AO, P1b, P1_b, O1);
  gemm_bt<0, 1><<<dim3(128, 4, 1), dim3(256, 1, 1), 0, stream>>>(O1, P2b, P2_b, out, 16384, 512, 1024);
}

// Round 13
// 168.579 us; speedup vs baseline: 1.2553x; 1.0073x over previous
//
#include <hip/hip_runtime.h>
#include <hip/hip_bf16.h>
#include <stdint.h>

typedef __attribute__((ext_vector_type(8))) short bf16x8;   // 8 bf16 (4 VGPRs)
typedef __attribute__((ext_vector_type(4))) short s16x4;
typedef __attribute__((ext_vector_type(4))) float f32x4;

#define MFMA16(a, b, c) __builtin_amdgcn_mfma_f32_16x16x32_bf16((a), (b), (c), 0, 0, 0)
// v_mfma_f32_16x16x16_bf16 — ROCm builtin keeps the gfx90a "_1k" name.
#define MFMAH(a, b, c) __builtin_amdgcn_mfma_f32_16x16x16bf16_1k((a), (b), (c), 0, 0, 0)

__device__ __forceinline__ void gload_lds16(const void* g, void* l) {
  // async global->LDS; HW adds lane*16 to the wave-uniform LDS base
  __builtin_amdgcn_global_load_lds((const __attribute__((address_space(1))) void*)g,
                                   (__attribute__((address_space(3))) void*)l, 16, 0, 0);
}

// ---- all f32->bf16 conversions fused into one grid-stride kernel ----
__global__ void cvt_all(const float* __restrict__ s0, const float* __restrict__ s1,
                        const float* __restrict__ s2, const float* __restrict__ s3,
                        const float* __restrict__ s4, const float* __restrict__ s5,
                        const float* __restrict__ s6,
                        __hip_bfloat16* __restrict__ d0, __hip_bfloat16* __restrict__ d1,
                        __hip_bfloat16* __restrict__ d2, __hip_bfloat16* __restrict__ d3,
                        __hip_bfloat16* __restrict__ d4, __hip_bfloat16* __restrict__ d5,
                        __hip_bfloat16* __restrict__ d6) {
  constexpr int e0 = 2097152;
  constexpr int e1 = e0 + 196608;
  constexpr int e2 = e1 + 131072;
  constexpr int e3 = e2 + 196608;
  constexpr int e4 = e3 + 196608;
  constexpr int e5 = e4 + 262144;
  constexpr int e6 = e5 + 131072;
  const int stride = gridDim.x * blockDim.x;
  for (int i = blockIdx.x * blockDim.x + threadIdx.x; i < e6; i += stride) {
    const float* s; __hip_bfloat16* d; int j;
    if (i < e0)      { s = s0; d = d0; j = i; }
    else if (i < e1) { s = s1; d = d1; j = i - e0; }
    else if (i < e2) { s = s2; d = d2; j = i - e1; }
    else if (i < e3) { s = s3; d = d3; j = i - e2; }
    else if (i < e4) { s = s4; d = d4; j = i - e3; }
    else if (i < e5) { s = s5; d = d5; j = i - e4; }
    else             { s = s6; d = d6; j = i - e5; }
    const float4 v = *(const float4*)(s + (size_t)j * 4);
    s16x4 o;
    __hip_bfloat16 h;
    h = __float2bfloat16(v.x); o[0] = *(short*)&h;
    h = __float2bfloat16(v.y); o[1] = *(short*)&h;
    h = __float2bfloat16(v.z); o[2] = *(short*)&h;
    h = __float2bfloat16(v.w); o[3] = *(short*)&h;
    *(s16x4*)((short*)d + (size_t)j * 4) = o;
  }
}

// LDS slot swizzle (proven: conflicts -> 0): LDS[row][slot] holds global chunk
// slot^((row>>1)&3); read slot for chunk lg: lg^((lr>>1)&3).

// C[M,N] = A[M,K] @ W[N,K]^T + bias. 128x128 tile, BK=32, 4 waves (m97 frame).
template <int RELU, int OUTMODE>
__global__ __launch_bounds__(256, 2) void gemm_bt(
    const __hip_bfloat16* __restrict__ Abf, const __hip_bfloat16* __restrict__ Wbf,
    const float* __restrict__ bias, void* __restrict__ Cv,
    int M, int N, int K) {
  __shared__ __align__(16) __hip_bfloat16 As[128 * 32];
  __shared__ __align__(16) __hip_bfloat16 Bs[128 * 32];
  const int t = threadIdx.x;
  const int w = t >> 6, lane = t & 63;
  const int lr = lane & 15, lg = lane >> 4;
  const int m0 = blockIdx.x * 128, n0 = blockIdx.y * 128;
  const int wr = (w >> 1) * 64, wc = (w & 1) * 64;

  const char* Ag = (const char*)Abf;
  const char* Wg = (const char*)Wbf;
  const size_t ldb = (size_t)K * 2;

  f32x4 acc[4][4] = {};

  const int o0 = (w << 10) + lane * 16;
  const int o1 = o0 + 4096;
  const int r0 = o0 >> 6, gc0 = ((((o0 >> 4) & 3) ^ ((r0 >> 1) & 3)) << 4);
  const int r1 = o1 >> 6, gc1 = ((((o1 >> 4) & 3) ^ ((r1 >> 1) & 3)) << 4);
  const int slx = (lg ^ ((lr >> 1) & 3)) << 4;

  for (int kt = 0; kt < K; kt += 32) {
    if (kt) __syncthreads();
    gload_lds16(Ag + (size_t)(m0 + r0) * ldb + kt * 2 + gc0, (char*)As + (w << 10));
    gload_lds16(Ag + (size_t)(m0 + r1) * ldb + kt * 2 + gc1, (char*)As + 4096 + (w << 10));
    gload_lds16(Wg + (size_t)(n0 + r0) * ldb + kt * 2 + gc0, (char*)Bs + (w << 10));
    gload_lds16(Wg + (size_t)(n0 + r1) * ldb + kt * 2 + gc1, (char*)Bs + 4096 + (w << 10));
    __syncthreads();

    bf16x8 af[4], bfv[4];
#pragma unroll
    for (int mi = 0; mi < 4; ++mi)
      af[mi] = *(const bf16x8*)((const char*)As + ((wr + mi * 16 + lr) << 6) + slx);
#pragma unroll
    for (int ni = 0; ni < 4; ++ni)
      bfv[ni] = *(const bf16x8*)((const char*)Bs + ((wc + ni * 16 + lr) << 6) + slx);
#pragma unroll
    for (int mi = 0; mi < 4; ++mi)
#pragma unroll
      for (int ni = 0; ni < 4; ++ni)
        acc[mi][ni] = MFMA16(af[mi], bfv[ni], acc[mi][ni]);
  }

#pragma unroll
  for (int ni = 0; ni < 4; ++ni) {
    const int col = n0 + wc + ni * 16 + lr;
    const float bv = bias[col];
#pragma unroll
    for (int mi = 0; mi < 4; ++mi) {
      const int row = m0 + wr + mi * 16 + lg * 4;
#pragma unroll
      for (int j = 0; j < 4; ++j) {
        float v = acc[mi][ni][j] + bv;
        if (RELU) v = fmaxf(v, 0.0f);
        if (OUTMODE == 0) {
          ((__hip_bfloat16*)Cv)[(size_t)(row + j) * N + col] = __float2bfloat16(v);
        } else if (OUTMODE == 1) {
          ((float*)Cv)[(size_t)(row + j) * N + col] = v;
        } else {
          const int rb = (row + j) >> 8, s = (row + j) & 255;
          const int hh = col >> 6, d = col & 63;
          ((__hip_bfloat16*)Cv)[(((size_t)(rb * 16 + hh) * 64 + d) << 8) + s] =
              __float2bfloat16(v);
        }
      }
    }
  }
}

// --- 256x256, BK=32, 8 waves, 4-buffer 128KB deep pipeline (round-12) ---
__device__ __forceinline__ void gemm256_body(
    const __hip_bfloat16* __restrict__ Abf, const __hip_bfloat16* __restrict__ Wbf,
    const float* __restrict__ bias, __hip_bfloat16* __restrict__ C,
    int N, int K, int outmode, int relu, int bx, int by) {
  __shared__ __align__(16) __hip_bfloat16 AsB[4][256 * 32];  // 4 x 16KB
  __shared__ __align__(16) __hip_bfloat16 BsB[4][256 * 32];  // 4 x 16KB
  const int t = threadIdx.x;
  const int w = t >> 6, lane = t & 63;
  const int lr = lane & 15, lg = lane >> 4;
  const int m0 = bx * 256, n0 = by * 256;
  const int wr = (w >> 2) * 128, wc = (w & 3) * 64;

  const char* Ag = (const char*)Abf;
  const char* Wg = (const char*)Wbf;
  const size_t ldb = (size_t)K * 2;

  f32x4 acc[8][4] = {};

  const int o0 = (w << 10) + lane * 16;
  const int o1 = o0 + 8192;
  const int r0 = o0 >> 6, gc0 = ((((o0 >> 4) & 3) ^ ((r0 >> 1) & 3)) << 4);
  const int r1 = o1 >> 6, gc1 = ((((o1 >> 4) & 3) ^ ((r1 >> 1) & 3)) << 4);
  const int slx = (lg ^ ((lr >> 1) & 3)) << 4;
  const int db0 = (w << 10);
  const int db1 = 8192 + (w << 10);

  auto STAGE_A = [&](int buf, int tile) {
    const int kt = tile << 5;
    gload_lds16(Ag + (size_t)(m0 + r0) * ldb + kt * 2 + gc0, (char*)AsB[buf] + db0);
    gload_lds16(Ag + (size_t)(m0 + r1) * ldb + kt * 2 + gc1, (char*)AsB[buf] + db1);
  };
  auto STAGE_B = [&](int buf, int tile) {
    const int kt = tile << 5;
    gload_lds16(Wg + (size_t)(n0 + r0) * ldb + kt * 2 + gc0, (char*)BsB[buf] + db0);
    gload_lds16(Wg + (size_t)(n0 + r1) * ldb + kt * 2 + gc1, (char*)BsB[buf] + db1);
  };

  auto tile_body = [&](int j, int stage_tile, int vmsel) {
    const int buf = j & 3;
    const int nbuf = stage_tile & 3;
    bf16x8 af0[4], af1[4], bfv[4];
#pragma unroll
    for (int mi = 0; mi < 4; ++mi)
      af0[mi] = *(const bf16x8*)((const char*)AsB[buf] + ((wr + mi * 16 + lr) << 6) + slx);
#pragma unroll
    for (int ni = 0; ni < 4; ++ni)
      bfv[ni] = *(const bf16x8*)((const char*)BsB[buf] + ((wc + ni * 16 + lr) << 6) + slx);
    if (stage_tile >= 0) STAGE_A(nbuf, stage_tile);
    asm volatile("s_barrier" ::: "memory");
    asm volatile("s_waitcnt lgkmcnt(0)" ::: "memory");
    __builtin_amdgcn_sched_barrier(0);
    __builtin_amdgcn_s_setprio(1);
#pragma unroll
    for (int mi = 0; mi < 4; ++mi)
#pragma unroll
      for (int ni = 0; ni < 4; ++ni)
        acc[mi][ni] = MFMA16(af0[mi], bfv[ni], acc[mi][ni]);
    __builtin_amdgcn_s_setprio(0);
    asm volatile("s_barrier" ::: "memory");
#pragma unroll
    for (int mi = 0; mi < 4; ++mi)
      af1[mi] = *(const bf16x8*)((const char*)AsB[buf] + ((wr + (mi + 4) * 16 + lr) << 6) + slx);
    if (stage_tile >= 0) STAGE_B(nbuf, stage_tile);
    if (vmsel == 0)      asm volatile("s_waitcnt vmcnt(8)" ::: "memory");
    else if (vmsel == 1) asm volatile("s_waitcnt vmcnt(4)" ::: "memory");
    else if (vmsel == 2) asm volatile("s_waitcnt vmcnt(0)" ::: "memory");
    asm volatile("s_barrier" ::: "memory");
    asm volatile("s_waitcnt lgkmcnt(0)" ::: "memory");
    __builtin_amdgcn_sched_barrier(0);
    __builtin_amdgcn_s_setprio(1);
#pragma unroll
    for (int mi = 0; mi < 4; ++mi)
#pragma unroll
      for (int ni = 0; ni < 4; ++ni)
        acc[mi + 4][ni] = MFMA16(af1[mi], bfv[ni], acc[mi + 4][ni]);
    __builtin_amdgcn_s_setprio(0);
    asm volatile("s_barrier" ::: "memory");
  };

  const int nt = K >> 5;
  STAGE_A(0, 0); STAGE_B(0, 0);
  STAGE_A(1, 1); STAGE_B(1, 1);
  STAGE_A(2, 2); STAGE_B(2, 2);
  asm volatile("s_waitcnt vmcnt(8)" ::: "memory");
  asm volatile("s_barrier" ::: "memory");
  for (int j = 0; j < nt - 3; ++j)
    tile_body(j, j + 3, 0);
  tile_body(nt - 3, -1, 1);
  tile_body(nt - 2, -1, 2);
  tile_body(nt - 1, -1, 3);

#pragma unroll
  for (int ni = 0; ni < 4; ++ni) {
    const int col = n0 + wc + ni * 16 + lr;
    const float bv = bias[col];
#pragma unroll
    for (int mi = 0; mi < 8; ++mi) {
      const int row = m0 + wr + mi * 16 + lg * 4;
#pragma unroll
      for (int j = 0; j < 4; ++j) {
        float v = acc[mi][ni][j] + bv;
        if (relu) v = fmaxf(v, 0.0f);
        if (outmode == 0) {
          C[(size_t)(row + j) * N + col] = __float2bfloat16(v);
        } else {
          const int rb = (row + j) >> 8, s = (row + j) & 255;
          const int hh = col >> 6, d = col & 63;
          C[(((size_t)(rb * 16 + hh) * 64 + d) << 8) + s] = __float2bfloat16(v);
        }
      }
    }
  }
}

// --- 256x256 LITE: 2-buffer 64KB -> 2 blocks/CU (TLP covers latency).
// Per K-tile: phase0 {reads || STAGE_A(next)} -> barrier -> 16 MFMA;
// phase1 {reads || STAGE_B(next)} -> barrier -> 16 MFMA -> vmcnt(0) -> barrier.
// Drain sits AFTER the MFMAs: next tile's loads get ~2 phases to fly, and the
// co-resident block fills any remaining stall.
__device__ __forceinline__ void gemm256_lite(
    const __hip_bfloat16* __restrict__ Abf, const __hip_bfloat16* __restrict__ Wbf,
    const float* __restrict__ bias, __hip_bfloat16* __restrict__ C,
    int N, int K, int outmode, int relu, int bx, int by) {
  __shared__ __align__(16) __hip_bfloat16 AsL[2][256 * 32];  // 2 x 16KB
  __shared__ __align__(16) __hip_bfloat16 BsL[2][256 * 32];  // 2 x 16KB
  const int t = threadIdx.x;
  const int w = t >> 6, lane = t & 63;
  const int lr = lane & 15, lg = lane >> 4;
  const int m0 = bx * 256, n0 = by * 256;
  const int wr = (w >> 2) * 128, wc = (w & 3) * 64;

  const char* Ag = (const char*)Abf;
  const char* Wg = (const char*)Wbf;
  const size_t ldb = (size_t)K * 2;

  f32x4 acc[8][4] = {};

  const int o0 = (w << 10) + lane * 16;
  const int o1 = o0 + 8192;
  const int r0 = o0 >> 6, gc0 = ((((o0 >> 4) & 3) ^ ((r0 >> 1) & 3)) << 4);
  const int r1 = o1 >> 6, gc1 = ((((o1 >> 4) & 3) ^ ((r1 >> 1) & 3)) << 4);
  const int slx = (lg ^ ((lr >> 1) & 3)) << 4;
  const int db0 = (w << 10);
  const int db1 = 8192 + (w << 10);

  auto STAGE_A = [&](int buf, int tile) {
    const int kt = tile << 5;
    gload_lds16(Ag + (size_t)(m0 + r0) * ldb + kt * 2 + gc0, (char*)AsL[buf] + db0);
    gload_lds16(Ag + (size_t)(m0 + r1) * ldb + kt * 2 + gc1, (char*)AsL[buf] + db1);
  };
  auto STAGE_B = [&](int buf, int tile) {
    const int kt = tile << 5;
    gload_lds16(Wg + (size_t)(n0 + r0) * ldb + kt * 2 + gc0, (char*)BsL[buf] + db0);
    gload_lds16(Wg + (size_t)(n0 + r1) * ldb + kt * 2 + gc1, (char*)BsL[buf] + db1);
  };

  const int nt = K >> 5;
  STAGE_A(0, 0); STAGE_B(0, 0);
  asm volatile("s_waitcnt vmcnt(0)" ::: "memory");
  asm volatile("s_barrier" ::: "memory");
  for (int j = 0; j < nt; ++j) {
    const int buf = j & 1;
    const int stage = (j + 1 < nt);
    bf16x8 af0[4], af1[4], bfv[4];
    // phase 0
#pragma unroll
    for (int mi = 0; mi < 4; ++mi)
      af0[mi] = *(const bf16x8*)((const char*)AsL[buf] + ((wr + mi * 16 + lr) << 6) + slx);
#pragma unroll
    for (int ni = 0; ni < 4; ++ni)
      bfv[ni] = *(const bf16x8*)((const char*)BsL[buf] + ((wc + ni * 16 + lr) << 6) + slx);
    if (stage) STAGE_A(buf ^ 1, j + 1);
    asm volatile("s_barrier" ::: "memory");
    asm volatile("s_waitcnt lgkmcnt(0)" ::: "memory");
    __builtin_amdgcn_sched_barrier(0);
    __builtin_amdgcn_s_setprio(1);
#pragma unroll
    for (int mi = 0; mi < 4; ++mi)
#pragma unroll
      for (int ni = 0; ni < 4; ++ni)
        acc[mi][ni] = MFMA16(af0[mi], bfv[ni], acc[mi][ni]);
    __builtin_amdgcn_s_setprio(0);
    asm volatile("s_barrier" ::: "memory");
    // phase 1
#pragma unroll
    for (int mi = 0; mi < 4; ++mi)
      af1[mi] = *(const bf16x8*)((const char*)AsL[buf] + ((wr + (mi + 4) * 16 + lr) << 6) + slx);
    if (stage) STAGE_B(buf ^ 1, j + 1);
    asm volatile("s_barrier" ::: "memory");
    asm volatile("s_waitcnt lgkmcnt(0)" ::: "memory");
    __builtin_amdgcn_sched_barrier(0);
    __builtin_amdgcn_s_setprio(1);
#pragma unroll
    for (int mi = 0; mi < 4; ++mi)
#pragma unroll
      for (int ni = 0; ni < 4; ++ni)
        acc[mi + 4][ni] = MFMA16(af1[mi], bfv[ni], acc[mi + 4][ni]);
    __builtin_amdgcn_s_setprio(0);
    if (stage) asm volatile("s_waitcnt vmcnt(0)" ::: "memory");
    asm volatile("s_barrier" ::: "memory");
  }

#pragma unroll
  for (int ni = 0; ni < 4; ++ni) {
    const int col = n0 + wc + ni * 16 + lr;
    const float bv = bias[col];
#pragma unroll
    for (int mi = 0; mi < 8; ++mi) {
      const int row = m0 + wr + mi * 16 + lg * 4;
#pragma unroll
      for (int j = 0; j < 4; ++j) {
        float v = acc[mi][ni][j] + bv;
        if (relu) v = fmaxf(v, 0.0f);
        if (outmode == 0) {
          C[(size_t)(row + j) * N + col] = __float2bfloat16(v);
        } else {
          const int rb = (row + j) >> 8, s = (row + j) & 255;
          const int hh = col >> 6, d = col & 63;
          C[(((size_t)(rb * 16 + hh) * 64 + d) << 8) + s] = __float2bfloat16(v);
        }
      }
    }
  }
}

// Q, K, V projections in ONE launch: 288 blocks on the 64KB LITE body ->
// 2 blocks/CU -> all 288 resident in one occupancy round (no straggler tail).
__global__ __launch_bounds__(512, 2) void gemm256_qkv(
    const __hip_bfloat16* __restrict__ xb, const __hip_bfloat16* __restrict__ ctxb,
    const __hip_bfloat16* __restrict__ Wq, const __hip_bfloat16* __restrict__ Wk,
    const __hip_bfloat16* __restrict__ Wv,
    const float* __restrict__ bq, const float* __restrict__ bk, const float* __restrict__ bv,
    __hip_bfloat16* __restrict__ Q, __hip_bfloat16* __restrict__ Kp,
    __hip_bfloat16* __restrict__ Vt) {
  const int bid = blockIdx.x;
  if (bid < 16) {
    gemm256_lite(ctxb, Wk, bk, Kp, 1024, 768, 0, 0, bid >> 2, bid & 3);
  } else if (bid < 32) {
    const int l = bid - 16;
    gemm256_lite(ctxb, Wv, bv, Vt, 1024, 768, 2, 0, l >> 2, l & 3);
  } else {
    const int l = bid - 32;                      // XCD-chunked remap (bijective)
    const int rb = (l & 7) * 32 + (l >> 3);
    gemm256_lite(xb, Wq, bq, Q, 1024, 512, 0, 0, rb >> 2, rb & 3);
  }
}

// P1 (ReLU): proven round-12 deep-pipeline body, XCD-chunked remap.
__global__ __launch_bounds__(512, 2) void gemm256_p1(
    const __hip_bfloat16* __restrict__ A, const __hip_bfloat16* __restrict__ W,
    const float* __restrict__ bias, __hip_bfloat16* __restrict__ C) {
  const int bid = blockIdx.x;  // 256 blocks
  const int rb = (bid & 7) * 32 + (bid >> 3);
  gemm256_body(A, W, bias, C, 1024, 1024, 0, 1, rb >> 2, rb & 3);
}

// Fused cross-attention (round-10, frozen): 8 waves/block, swapped QK^T,
// register P, 16x16x16 PV.
__global__ __launch_bounds__(512, 4) void attn_fused(
    const __hip_bfloat16* __restrict__ Qb, const __hip_bfloat16* __restrict__ Kb,
    const __hip_bfloat16* __restrict__ Vtg, const float* __restrict__ padm,
    const float* __restrict__ seqm, __hip_bfloat16* __restrict__ O) {
  constexpr int S = 256, E = 1024, Nq = 4096;
  constexpr float NEGV = -1e9f;
  __shared__ __align__(16) char smem[65536];
  char* VtB = smem;
  char* KsB = smem + 32768;

  const int t = threadIdx.x;           // 0..511
  const int w = t >> 6, lane = t & 63; // 8 waves
  const int lr = lane & 15, lg = lane >> 4;
  const int h = blockIdx.y, b = blockIdx.z;

  const char* Kg = (const char*)(Kb + (size_t)b * S * E + h * 64);
#pragma unroll
  for (int i = 0; i < 4; ++i) {
    const int o = ((i * 8 + w) << 10) + lane * 16;
    const int s = o >> 7, bc = o & 127;
    gload_lds16(Kg + (size_t)s * (E * 2) + (bc ^ ((s & 7) << 4)), KsB + ((i * 8 + w) << 10));
  }
  const char* Vg = (const char*)Vtg + ((size_t)(b * 16 + h) << 15);
#pragma unroll
  for (int i = 0; i < 4; ++i) {
    const int o = ((i * 8 + w) << 10) + lane * 16;
    const int d = o >> 9, c = o & 511;
    gload_lds16(Vg + (d << 9) + (c ^ ((d & 7) << 4)), VtB + ((i * 8 + w) << 10));
  }

  const int qw = blockIdx.x * 128 + w * 16;
  const short* Qg = (const short*)Qb + (size_t)(b * Nq + qw + lr) * E + h * 64;
  const bf16x8 aq0 = *(const bf16x8*)(Qg + (lg << 3));
  const bf16x8 aq1 = *(const bf16x8*)(Qg + 32 + (lg << 3));
  const float padq = padm[(size_t)b * Nq + qw + lr];
  const float qbias = (padq != 0.f) ? 0.f : NEGV;

  __syncthreads();

  const int swz = (lr & 7) << 4;
  f32x4 o[4] = {};
  float ssum = 0.f;
#pragma unroll
  for (int ni = 0; ni < 16; ++ni) {
    const int s = ni * 16 + lr;
    const bf16x8 bk0 = *(const bf16x8*)(KsB + (s << 7) + ((lg << 4) ^ swz));
    const bf16x8 bk1 = *(const bf16x8*)(KsB + (s << 7) + ((64 + (lg << 4)) ^ swz));
    f32x4 a = {};
    a = MFMA16(bk0, aq0, a);
    a = MFMA16(bk1, aq1, a);

    const float4 sm4 = *(const float4*)(seqm + (size_t)b * S + ni * 16 + lg * 4);
    const float e0 = __expf(a[0] * 0.125f + ((sm4.x != 0.f ? 0.f : NEGV) + qbias));
    const float e1 = __expf(a[1] * 0.125f + ((sm4.y != 0.f ? 0.f : NEGV) + qbias));
    const float e2 = __expf(a[2] * 0.125f + ((sm4.z != 0.f ? 0.f : NEGV) + qbias));
    const float e3 = __expf(a[3] * 0.125f + ((sm4.w != 0.f ? 0.f : NEGV) + qbias));
    ssum += (e0 + e1) + (e2 + e3);

    s16x4 pf;
    __hip_bfloat16 hh;
    hh = __float2bfloat16(e0); pf[0] = *(short*)&hh;
    hh = __float2bfloat16(e1); pf[1] = *(short*)&hh;
    hh = __float2bfloat16(e2); pf[2] = *(short*)&hh;
    hh = __float2bfloat16(e3); pf[3] = *(short*)&hh;

    const int sb = (ni * 32 + lg * 8);
#pragma unroll
    for (int nd = 0; nd < 4; ++nd) {
      const int d = nd * 16 + lr;
      const s16x4 bv = *(const s16x4*)(VtB + (d << 9) + (sb ^ swz));
      o[nd] = MFMAH(pf, bv, o[nd]);
    }
  }

  ssum += __shfl_xor(ssum, 16);
  ssum += __shfl_xor(ssum, 32);
  const float inv = 1.0f / ssum;
  float invj[4];
#pragma unroll
  for (int j = 0; j < 4; ++j) invj[j] = __shfl(inv, lg * 4 + j);

  __hip_bfloat16* Og = O + (size_t)(b * Nq + qw) * E + h * 64;
#pragma unroll
  for (int nd = 0; nd < 4; ++nd)
#pragma unroll
    for (int j = 0; j < 4; ++j)
      Og[(size_t)(lg * 4 + j) * E + nd * 16 + lr] = __float2bfloat16(o[nd][j] * invj[j]);
}

extern "C" void kernel_launch(void* const* d_in, const int* in_sizes, int n_in,
                              void* d_out, int out_size, void* d_ws, size_t ws_size,
                              hipStream_t stream) {
  const float* x    = (const float*)d_in[0];
  const float* ctx  = (const float*)d_in[1];
  const float* padm = (const float*)d_in[2];
  const float* seqm = (const float*)d_in[3];
  const float* Wq_w = (const float*)d_in[4];
  const float* Wq_b = (const float*)d_in[5];
  const float* Wk_w = (const float*)d_in[6];
  const float* Wk_b = (const float*)d_in[7];
  const float* Wv_w = (const float*)d_in[8];
  const float* Wv_b = (const float*)d_in[9];
  const float* P1_w = (const float*)d_in[10];
  const float* P1_b = (const float*)d_in[11];
  const float* P2_w = (const float*)d_in[12];
  const float* P2_b = (const float*)d_in[13];
  float* out = (float*)d_out;

  char* ws = (char*)d_ws;
  size_t off = 0;
  auto alloc = [&](size_t bytes) { char* p = ws + off; off += (bytes + 255) & ~(size_t)255; return p; };
  __hip_bfloat16* Q    = (__hip_bfloat16*)alloc(16384ull * 1024 * 2);  // 32MB (later O1)
  __hip_bfloat16* AO   = (__hip_bfloat16*)alloc(16384ull * 1024 * 2);  // 32MB
  __hip_bfloat16* xb   = (__hip_bfloat16*)alloc(16384ull * 512 * 2);   // 16MB
  __hip_bfloat16* ctxb = (__hip_bfloat16*)alloc(1024ull * 768 * 2);
  __hip_bfloat16* Kp   = (__hip_bfloat16*)alloc(1024ull * 1024 * 2);
  __hip_bfloat16* Vt   = (__hip_bfloat16*)alloc(1024ull * 1024 * 2);   // V^T [b,h][d][s]
  __hip_bfloat16* Wqb  = (__hip_bfloat16*)alloc(1024ull * 512 * 2);
  __hip_bfloat16* Wkb  = (__hip_bfloat16*)alloc(1024ull * 768 * 2);
  __hip_bfloat16* Wvb  = (__hip_bfloat16*)alloc(1024ull * 768 * 2);
  __hip_bfloat16* P1b  = (__hip_bfloat16*)alloc(1024ull * 1024 * 2);
  __hip_bfloat16* P2b  = (__hip_bfloat16*)alloc(512ull * 1024 * 2);
  __hip_bfloat16* O1   = Q;  // reuse Q after attention

  cvt_all<<<dim3(2048, 1, 1), dim3(256, 1, 1), 0, stream>>>(
      x, ctx, Wq_w, Wk_w, Wv_w, P1_w, P2_w, xb, ctxb, Wqb, Wkb, Wvb, P1b, P2b);

  gemm256_qkv<<<dim3(288, 1, 1), dim3(512, 1, 1), 0, stream>>>(
      xb, ctxb, Wqb, Wkb, Wvb, Wq_b, Wk_b, Wv_b, Q, Kp, Vt);
  attn_fused<<<dim3(32, 16, 4), dim3(512, 1, 1), 0, stream>>>(Q, Kp, Vt, padm, seqm, AO);
  gemm256_p1<<<dim3(256, 1, 1), dim3(512, 1, 1), 0, stream>>>(AO, P1b, P1_b, O1);
  gemm_bt<0, 1><<<dim3(128, 4, 1), dim3(256, 1, 1), 0, stream>>>(O1, P2b, P2_b, out, 16384, 512, 1024);
}

// Round 14
// 163.296 us; speedup vs baseline: 1.2959x; 1.0324x over previous
//
#include <hip/hip_runtime.h>
#include <hip/hip_bf16.h>
#include <stdint.h>

typedef __attribute__((ext_vector_type(8))) short bf16x8;   // 8 bf16 (4 VGPRs)
typedef __attribute__((ext_vector_type(4))) short s16x4;
typedef __attribute__((ext_vector_type(4))) float f32x4;

#define MFMA16(a, b, c) __builtin_amdgcn_mfma_f32_16x16x32_bf16((a), (b), (c), 0, 0, 0)
// v_mfma_f32_16x16x16_bf16 — ROCm builtin keeps the gfx90a "_1k" name.
#define MFMAH(a, b, c) __builtin_amdgcn_mfma_f32_16x16x16bf16_1k((a), (b), (c), 0, 0, 0)

__device__ __forceinline__ void gload_lds16(const void* g, void* l) {
  // async global->LDS; HW adds lane*16 to the wave-uniform LDS base
  __builtin_amdgcn_global_load_lds((const __attribute__((address_space(1))) void*)g,
                                   (__attribute__((address_space(3))) void*)l, 16, 0, 0);
}

// ---- all f32->bf16 conversions fused into one grid-stride kernel ----
__global__ void cvt_all(const float* __restrict__ s0, const float* __restrict__ s1,
                        const float* __restrict__ s2, const float* __restrict__ s3,
                        const float* __restrict__ s4, const float* __restrict__ s5,
                        const float* __restrict__ s6,
                        __hip_bfloat16* __restrict__ d0, __hip_bfloat16* __restrict__ d1,
                        __hip_bfloat16* __restrict__ d2, __hip_bfloat16* __restrict__ d3,
                        __hip_bfloat16* __restrict__ d4, __hip_bfloat16* __restrict__ d5,
                        __hip_bfloat16* __restrict__ d6) {
  constexpr int e0 = 2097152;
  constexpr int e1 = e0 + 196608;
  constexpr int e2 = e1 + 131072;
  constexpr int e3 = e2 + 196608;
  constexpr int e4 = e3 + 196608;
  constexpr int e5 = e4 + 262144;
  constexpr int e6 = e5 + 131072;
  const int stride = gridDim.x * blockDim.x;
  for (int i = blockIdx.x * blockDim.x + threadIdx.x; i < e6; i += stride) {
    const float* s; __hip_bfloat16* d; int j;
    if (i < e0)      { s = s0; d = d0; j = i; }
    else if (i < e1) { s = s1; d = d1; j = i - e0; }
    else if (i < e2) { s = s2; d = d2; j = i - e1; }
    else if (i < e3) { s = s3; d = d3; j = i - e2; }
    else if (i < e4) { s = s4; d = d4; j = i - e3; }
    else if (i < e5) { s = s5; d = d5; j = i - e4; }
    else             { s = s6; d = d6; j = i - e5; }
    const float4 v = *(const float4*)(s + (size_t)j * 4);
    s16x4 o;
    __hip_bfloat16 h;
    h = __float2bfloat16(v.x); o[0] = *(short*)&h;
    h = __float2bfloat16(v.y); o[1] = *(short*)&h;
    h = __float2bfloat16(v.z); o[2] = *(short*)&h;
    h = __float2bfloat16(v.w); o[3] = *(short*)&h;
    *(s16x4*)((short*)d + (size_t)j * 4) = o;
  }
}

// LDS slot swizzle (proven: conflicts -> 0): LDS[row][slot] holds global chunk
// slot^((row>>1)&3); read slot for chunk lg: lg^((lr>>1)&3).

// C[M,N] = A[M,K] @ W[N,K]^T + bias. 128x128 tile, BK=32, 4 waves (m97 frame).
template <int RELU, int OUTMODE>
__global__ __launch_bounds__(256, 2) void gemm_bt(
    const __hip_bfloat16* __restrict__ Abf, const __hip_bfloat16* __restrict__ Wbf,
    const float* __restrict__ bias, void* __restrict__ Cv,
    int M, int N, int K) {
  __shared__ __align__(16) __hip_bfloat16 As[128 * 32];
  __shared__ __align__(16) __hip_bfloat16 Bs[128 * 32];
  const int t = threadIdx.x;
  const int w = t >> 6, lane = t & 63;
  const int lr = lane & 15, lg = lane >> 4;
  const int m0 = blockIdx.x * 128, n0 = blockIdx.y * 128;
  const int wr = (w >> 1) * 64, wc = (w & 1) * 64;

  const char* Ag = (const char*)Abf;
  const char* Wg = (const char*)Wbf;
  const size_t ldb = (size_t)K * 2;

  f32x4 acc[4][4] = {};

  const int o0 = (w << 10) + lane * 16;
  const int o1 = o0 + 4096;
  const int r0 = o0 >> 6, gc0 = ((((o0 >> 4) & 3) ^ ((r0 >> 1) & 3)) << 4);
  const int r1 = o1 >> 6, gc1 = ((((o1 >> 4) & 3) ^ ((r1 >> 1) & 3)) << 4);
  const int slx = (lg ^ ((lr >> 1) & 3)) << 4;

  for (int kt = 0; kt < K; kt += 32) {
    if (kt) __syncthreads();
    gload_lds16(Ag + (size_t)(m0 + r0) * ldb + kt * 2 + gc0, (char*)As + (w << 10));
    gload_lds16(Ag + (size_t)(m0 + r1) * ldb + kt * 2 + gc1, (char*)As + 4096 + (w << 10));
    gload_lds16(Wg + (size_t)(n0 + r0) * ldb + kt * 2 + gc0, (char*)Bs + (w << 10));
    gload_lds16(Wg + (size_t)(n0 + r1) * ldb + kt * 2 + gc1, (char*)Bs + 4096 + (w << 10));
    __syncthreads();

    bf16x8 af[4], bfv[4];
#pragma unroll
    for (int mi = 0; mi < 4; ++mi)
      af[mi] = *(const bf16x8*)((const char*)As + ((wr + mi * 16 + lr) << 6) + slx);
#pragma unroll
    for (int ni = 0; ni < 4; ++ni)
      bfv[ni] = *(const bf16x8*)((const char*)Bs + ((wc + ni * 16 + lr) << 6) + slx);
#pragma unroll
    for (int mi = 0; mi < 4; ++mi)
#pragma unroll
      for (int ni = 0; ni < 4; ++ni)
        acc[mi][ni] = MFMA16(af[mi], bfv[ni], acc[mi][ni]);
  }

#pragma unroll
  for (int ni = 0; ni < 4; ++ni) {
    const int col = n0 + wc + ni * 16 + lr;
    const float bv = bias[col];
#pragma unroll
    for (int mi = 0; mi < 4; ++mi) {
      const int row = m0 + wr + mi * 16 + lg * 4;
#pragma unroll
      for (int j = 0; j < 4; ++j) {
        float v = acc[mi][ni][j] + bv;
        if (RELU) v = fmaxf(v, 0.0f);
        if (OUTMODE == 0) {
          ((__hip_bfloat16*)Cv)[(size_t)(row + j) * N + col] = __float2bfloat16(v);
        } else if (OUTMODE == 1) {
          ((float*)Cv)[(size_t)(row + j) * N + col] = v;
        } else {
          const int rb = (row + j) >> 8, s = (row + j) & 255;
          const int hh = col >> 6, d = col & 63;
          ((__hip_bfloat16*)Cv)[(((size_t)(rb * 16 + hh) * 64 + d) << 8) + s] =
              __float2bfloat16(v);
        }
      }
    }
  }
}

// --- 256x256 LITE: 2-buffer 64KB -> 2 blocks/CU (TLP covers stalls).
// Per K-tile: phase0 {reads || STAGE_A(next)} -> barrier -> 16 MFMA;
// phase1 {reads || STAGE_B(next)} -> barrier -> 16 MFMA -> vmcnt(0) -> barrier.
__device__ __forceinline__ void gemm256_lite(
    const __hip_bfloat16* __restrict__ Abf, const __hip_bfloat16* __restrict__ Wbf,
    const float* __restrict__ bias, __hip_bfloat16* __restrict__ C,
    int N, int K, int outmode, int relu, int bx, int by) {
  __shared__ __align__(16) __hip_bfloat16 AsL[2][256 * 32];  // 2 x 16KB
  __shared__ __align__(16) __hip_bfloat16 BsL[2][256 * 32];  // 2 x 16KB
  const int t = threadIdx.x;
  const int w = t >> 6, lane = t & 63;
  const int lr = lane & 15, lg = lane >> 4;
  const int m0 = bx * 256, n0 = by * 256;
  const int wr = (w >> 2) * 128, wc = (w & 3) * 64;

  const char* Ag = (const char*)Abf;
  const char* Wg = (const char*)Wbf;
  const size_t ldb = (size_t)K * 2;

  f32x4 acc[8][4] = {};

  const int o0 = (w << 10) + lane * 16;
  const int o1 = o0 + 8192;
  const int r0 = o0 >> 6, gc0 = ((((o0 >> 4) & 3) ^ ((r0 >> 1) & 3)) << 4);
  const int r1 = o1 >> 6, gc1 = ((((o1 >> 4) & 3) ^ ((r1 >> 1) & 3)) << 4);
  const int slx = (lg ^ ((lr >> 1) & 3)) << 4;
  const int db0 = (w << 10);
  const int db1 = 8192 + (w << 10);

  auto STAGE_A = [&](int buf, int tile) {
    const int kt = tile << 5;
    gload_lds16(Ag + (size_t)(m0 + r0) * ldb + kt * 2 + gc0, (char*)AsL[buf] + db0);
    gload_lds16(Ag + (size_t)(m0 + r1) * ldb + kt * 2 + gc1, (char*)AsL[buf] + db1);
  };
  auto STAGE_B = [&](int buf, int tile) {
    const int kt = tile << 5;
    gload_lds16(Wg + (size_t)(n0 + r0) * ldb + kt * 2 + gc0, (char*)BsL[buf] + db0);
    gload_lds16(Wg + (size_t)(n0 + r1) * ldb + kt * 2 + gc1, (char*)BsL[buf] + db1);
  };

  const int nt = K >> 5;
  STAGE_A(0, 0); STAGE_B(0, 0);
  asm volatile("s_waitcnt vmcnt(0)" ::: "memory");
  asm volatile("s_barrier" ::: "memory");
  for (int j = 0; j < nt; ++j) {
    const int buf = j & 1;
    const int stage = (j + 1 < nt);
    bf16x8 af0[4], af1[4], bfv[4];
    // phase 0
#pragma unroll
    for (int mi = 0; mi < 4; ++mi)
      af0[mi] = *(const bf16x8*)((const char*)AsL[buf] + ((wr + mi * 16 + lr) << 6) + slx);
#pragma unroll
    for (int ni = 0; ni < 4; ++ni)
      bfv[ni] = *(const bf16x8*)((const char*)BsL[buf] + ((wc + ni * 16 + lr) << 6) + slx);
    if (stage) STAGE_A(buf ^ 1, j + 1);
    asm volatile("s_barrier" ::: "memory");
    asm volatile("s_waitcnt lgkmcnt(0)" ::: "memory");
    __builtin_amdgcn_sched_barrier(0);
    __builtin_amdgcn_s_setprio(1);
#pragma unroll
    for (int mi = 0; mi < 4; ++mi)
#pragma unroll
      for (int ni = 0; ni < 4; ++ni)
        acc[mi][ni] = MFMA16(af0[mi], bfv[ni], acc[mi][ni]);
    __builtin_amdgcn_s_setprio(0);
    asm volatile("s_barrier" ::: "memory");
    // phase 1
#pragma unroll
    for (int mi = 0; mi < 4; ++mi)
      af1[mi] = *(const bf16x8*)((const char*)AsL[buf] + ((wr + (mi + 4) * 16 + lr) << 6) + slx);
    if (stage) STAGE_B(buf ^ 1, j + 1);
    asm volatile("s_barrier" ::: "memory");
    asm volatile("s_waitcnt lgkmcnt(0)" ::: "memory");
    __builtin_amdgcn_sched_barrier(0);
    __builtin_amdgcn_s_setprio(1);
#pragma unroll
    for (int mi = 0; mi < 4; ++mi)
#pragma unroll
      for (int ni = 0; ni < 4; ++ni)
        acc[mi + 4][ni] = MFMA16(af1[mi], bfv[ni], acc[mi + 4][ni]);
    __builtin_amdgcn_s_setprio(0);
    if (stage) asm volatile("s_waitcnt vmcnt(0)" ::: "memory");
    asm volatile("s_barrier" ::: "memory");
  }

#pragma unroll
  for (int ni = 0; ni < 4; ++ni) {
    const int col = n0 + wc + ni * 16 + lr;
    const float bv = bias[col];
#pragma unroll
    for (int mi = 0; mi < 8; ++mi) {
      const int row = m0 + wr + mi * 16 + lg * 4;
#pragma unroll
      for (int j = 0; j < 4; ++j) {
        float v = acc[mi][ni][j] + bv;
        if (relu) v = fmaxf(v, 0.0f);
        if (outmode == 0) {
          C[(size_t)(row + j) * N + col] = __float2bfloat16(v);
        } else {
          const int rb = (row + j) >> 8, s = (row + j) & 255;
          const int hh = col >> 6, d = col & 63;
          C[(((size_t)(rb * 16 + hh) * 64 + d) << 8) + s] = __float2bfloat16(v);
        }
      }
    }
  }
}

// Q, K, V projections in ONE launch: 288 blocks on the 64KB LITE body ->
// 2 blocks/CU -> all 288 resident in one occupancy round.
__global__ __launch_bounds__(512, 2) void gemm256_qkv(
    const __hip_bfloat16* __restrict__ xb, const __hip_bfloat16* __restrict__ ctxb,
    const __hip_bfloat16* __restrict__ Wq, const __hip_bfloat16* __restrict__ Wk,
    const __hip_bfloat16* __restrict__ Wv,
    const float* __restrict__ bq, const float* __restrict__ bk, const float* __restrict__ bv,
    __hip_bfloat16* __restrict__ Q, __hip_bfloat16* __restrict__ Kp,
    __hip_bfloat16* __restrict__ Vt) {
  const int bid = blockIdx.x;
  if (bid < 16) {
    gemm256_lite(ctxb, Wk, bk, Kp, 1024, 768, 0, 0, bid >> 2, bid & 3);
  } else if (bid < 32) {
    const int l = bid - 16;
    gemm256_lite(ctxb, Wv, bv, Vt, 1024, 768, 2, 0, l >> 2, l & 3);
  } else {
    const int l = bid - 32;                      // XCD-chunked remap (bijective)
    const int rb = (l & 7) * 32 + (l >> 3);
    gemm256_lite(xb, Wq, bq, Q, 1024, 512, 0, 0, rb >> 2, rb & 3);
  }
}

// P1 (ReLU): now on the LITE body too (2 blocks/CU beats deep pipeline at
// 1 block/CU — round-13 A/B: 786 vs 693 TF). XCD-chunked remap retained.
__global__ __launch_bounds__(512, 2) void gemm256_p1(
    const __hip_bfloat16* __restrict__ A, const __hip_bfloat16* __restrict__ W,
    const float* __restrict__ bias, __hip_bfloat16* __restrict__ C) {
  const int bid = blockIdx.x;  // 256 blocks
  const int rb = (bid & 7) * 32 + (bid >> 3);
  gemm256_lite(A, W, bias, C, 1024, 1024, 0, 1, rb >> 2, rb & 3);
}

// Fused cross-attention (round-10, frozen): 8 waves/block, swapped QK^T,
// register P, 16x16x16 PV.
__global__ __launch_bounds__(512, 4) void attn_fused(
    const __hip_bfloat16* __restrict__ Qb, const __hip_bfloat16* __restrict__ Kb,
    const __hip_bfloat16* __restrict__ Vtg, const float* __restrict__ padm,
    const float* __restrict__ seqm, __hip_bfloat16* __restrict__ O) {
  constexpr int S = 256, E = 1024, Nq = 4096;
  constexpr float NEGV = -1e9f;
  __shared__ __align__(16) char smem[65536];
  char* VtB = smem;
  char* KsB = smem + 32768;

  const int t = threadIdx.x;           // 0..511
  const int w = t >> 6, lane = t & 63; // 8 waves
  const int lr = lane & 15, lg = lane >> 4;
  const int h = blockIdx.y, b = blockIdx.z;

  const char* Kg = (const char*)(Kb + (size_t)b * S * E + h * 64);
#pragma unroll
  for (int i = 0; i < 4; ++i) {
    const int o = ((i * 8 + w) << 10) + lane * 16;
    const int s = o >> 7, bc = o & 127;
    gload_lds16(Kg + (size_t)s * (E * 2) + (bc ^ ((s & 7) << 4)), KsB + ((i * 8 + w) << 10));
  }
  const char* Vg = (const char*)Vtg + ((size_t)(b * 16 + h) << 15);
#pragma unroll
  for (int i = 0; i < 4; ++i) {
    const int o = ((i * 8 + w) << 10) + lane * 16;
    const int d = o >> 9, c = o & 511;
    gload_lds16(Vg + (d << 9) + (c ^ ((d & 7) << 4)), VtB + ((i * 8 + w) << 10));
  }

  const int qw = blockIdx.x * 128 + w * 16;
  const short* Qg = (const short*)Qb + (size_t)(b * Nq + qw + lr) * E + h * 64;
  const bf16x8 aq0 = *(const bf16x8*)(Qg + (lg << 3));
  const bf16x8 aq1 = *(const bf16x8*)(Qg + 32 + (lg << 3));
  const float padq = padm[(size_t)b * Nq + qw + lr];
  const float qbias = (padq != 0.f) ? 0.f : NEGV;

  __syncthreads();

  const int swz = (lr & 7) << 4;
  f32x4 o[4] = {};
  float ssum = 0.f;
#pragma unroll
  for (int ni = 0; ni < 16; ++ni) {
    const int s = ni * 16 + lr;
    const bf16x8 bk0 = *(const bf16x8*)(KsB + (s << 7) + ((lg << 4) ^ swz));
    const bf16x8 bk1 = *(const bf16x8*)(KsB + (s << 7) + ((64 + (lg << 4)) ^ swz));
    f32x4 a = {};
    a = MFMA16(bk0, aq0, a);
    a = MFMA16(bk1, aq1, a);

    const float4 sm4 = *(const float4*)(seqm + (size_t)b * S + ni * 16 + lg * 4);
    const float e0 = __expf(a[0] * 0.125f + ((sm4.x != 0.f ? 0.f : NEGV) + qbias));
    const float e1 = __expf(a[1] * 0.125f + ((sm4.y != 0.f ? 0.f : NEGV) + qbias));
    const float e2 = __expf(a[2] * 0.125f + ((sm4.z != 0.f ? 0.f : NEGV) + qbias));
    const float e3 = __expf(a[3] * 0.125f + ((sm4.w != 0.f ? 0.f : NEGV) + qbias));
    ssum += (e0 + e1) + (e2 + e3);

    s16x4 pf;
    __hip_bfloat16 hh;
    hh = __float2bfloat16(e0); pf[0] = *(short*)&hh;
    hh = __float2bfloat16(e1); pf[1] = *(short*)&hh;
    hh = __float2bfloat16(e2); pf[2] = *(short*)&hh;
    hh = __float2bfloat16(e3); pf[3] = *(short*)&hh;

    const int sb = (ni * 32 + lg * 8);
#pragma unroll
    for (int nd = 0; nd < 4; ++nd) {
      const int d = nd * 16 + lr;
      const s16x4 bv = *(const s16x4*)(VtB + (d << 9) + (sb ^ swz));
      o[nd] = MFMAH(pf, bv, o[nd]);
    }
  }

  ssum += __shfl_xor(ssum, 16);
  ssum += __shfl_xor(ssum, 32);
  const float inv = 1.0f / ssum;
  float invj[4];
#pragma unroll
  for (int j = 0; j < 4; ++j) invj[j] = __shfl(inv, lg * 4 + j);

  __hip_bfloat16* Og = O + (size_t)(b * Nq + qw) * E + h * 64;
#pragma unroll
  for (int nd = 0; nd < 4; ++nd)
#pragma unroll
    for (int j = 0; j < 4; ++j)
      Og[(size_t)(lg * 4 + j) * E + nd * 16 + lr] = __float2bfloat16(o[nd][j] * invj[j]);
}

extern "C" void kernel_launch(void* const* d_in, const int* in_sizes, int n_in,
                              void* d_out, int out_size, void* d_ws, size_t ws_size,
                              hipStream_t stream) {
  const float* x    = (const float*)d_in[0];
  const float* ctx  = (const float*)d_in[1];
  const float* padm = (const float*)d_in[2];
  const float* seqm = (const float*)d_in[3];
  const float* Wq_w = (const float*)d_in[4];
  const float* Wq_b = (const float*)d_in[5];
  const float* Wk_w = (const float*)d_in[6];
  const float* Wk_b = (const float*)d_in[7];
  const float* Wv_w = (const float*)d_in[8];
  const float* Wv_b = (const float*)d_in[9];
  const float* P1_w = (const float*)d_in[10];
  const float* P1_b = (const float*)d_in[11];
  const float* P2_w = (const float*)d_in[12];
  const float* P2_b = (const float*)d_in[13];
  float* out = (float*)d_out;

  char* ws = (char*)d_ws;
  size_t off = 0;
  auto alloc = [&](size_t bytes) { char* p = ws + off; off += (bytes + 255) & ~(size_t)255; return p; };
  __hip_bfloat16* Q    = (__hip_bfloat16*)alloc(16384ull * 1024 * 2);  // 32MB (later O1)
  __hip_bfloat16* AO   = (__hip_bfloat16*)alloc(16384ull * 1024 * 2);  // 32MB
  __hip_bfloat16* xb   = (__hip_bfloat16*)alloc(16384ull * 512 * 2);   // 16MB
  __hip_bfloat16* ctxb = (__hip_bfloat16*)alloc(1024ull * 768 * 2);
  __hip_bfloat16* Kp   = (__hip_bfloat16*)alloc(1024ull * 1024 * 2);
  __hip_bfloat16* Vt   = (__hip_bfloat16*)alloc(1024ull * 1024 * 2);   // V^T [b,h][d][s]
  __hip_bfloat16* Wqb  = (__hip_bfloat16*)alloc(1024ull * 512 * 2);
  __hip_bfloat16* Wkb  = (__hip_bfloat16*)alloc(1024ull * 768 * 2);
  __hip_bfloat16* Wvb  = (__hip_bfloat16*)alloc(1024ull * 768 * 2);
  __hip_bfloat16* P1b  = (__hip_bfloat16*)alloc(1024ull * 1024 * 2);
  __hip_bfloat16* P2b  = (__hip_bfloat16*)alloc(512ull * 1024 * 2);
  __hip_bfloat16* O1   = Q;  // reuse Q after attention

  cvt_all<<<dim3(2048, 1, 1), dim3(256, 1, 1), 0, stream>>>(
      x, ctx, Wq_w, Wk_w, Wv_w, P1_w, P2_w, xb, ctxb, Wqb, Wkb, Wvb, P1b, P2b);

  gemm256_qkv<<<dim3(288, 1, 1), dim3(512, 1, 1), 0, stream>>>(
      xb, ctxb, Wqb, Wkb, Wvb, Wq_b, Wk_b, Wv_b, Q, Kp, Vt);
  attn_fused<<<dim3(32, 16, 4), dim3(512, 1, 1), 0, stream>>>(Q, Kp, Vt, padm, seqm, AO);
  gemm256_p1<<<dim3(256, 1, 1), dim3(512, 1, 1), 0, stream>>>(AO, P1b, P1_b, O1);
  gemm_bt<0, 1><<<dim3(128, 4, 1), dim3(256, 1, 1), 0, stream>>>(O1, P2b, P2_b, out, 16384, 512, 1024);
}

// Round 15
// 155.961 us; speedup vs baseline: 1.3569x; 1.0470x over previous
//
#include <hip/hip_runtime.h>
#include <hip/hip_bf16.h>
#include <stdint.h>

typedef __attribute__((ext_vector_type(8))) short bf16x8;   // 8 bf16 (4 VGPRs)
typedef __attribute__((ext_vector_type(4))) short s16x4;
typedef __attribute__((ext_vector_type(4))) float f32x4;

#define MFMA16(a, b, c) __builtin_amdgcn_mfma_f32_16x16x32_bf16((a), (b), (c), 0, 0, 0)
// v_mfma_f32_16x16x16_bf16 — ROCm builtin keeps the gfx90a "_1k" name.
#define MFMAH(a, b, c) __builtin_amdgcn_mfma_f32_16x16x16bf16_1k((a), (b), (c), 0, 0, 0)

__device__ __forceinline__ void gload_lds16(const void* g, void* l) {
  // async global->LDS; HW adds lane*16 to the wave-uniform LDS base
  __builtin_amdgcn_global_load_lds((const __attribute__((address_space(1))) void*)g,
                                   (__attribute__((address_space(3))) void*)l, 16, 0, 0);
}

// ---- all f32->bf16 conversions fused into one grid-stride kernel ----
__global__ void cvt_all(const float* __restrict__ s0, const float* __restrict__ s1,
                        const float* __restrict__ s2, const float* __restrict__ s3,
                        const float* __restrict__ s4, const float* __restrict__ s5,
                        const float* __restrict__ s6,
                        __hip_bfloat16* __restrict__ d0, __hip_bfloat16* __restrict__ d1,
                        __hip_bfloat16* __restrict__ d2, __hip_bfloat16* __restrict__ d3,
                        __hip_bfloat16* __restrict__ d4, __hip_bfloat16* __restrict__ d5,
                        __hip_bfloat16* __restrict__ d6) {
  constexpr int e0 = 2097152;
  constexpr int e1 = e0 + 196608;
  constexpr int e2 = e1 + 131072;
  constexpr int e3 = e2 + 196608;
  constexpr int e4 = e3 + 196608;
  constexpr int e5 = e4 + 262144;
  constexpr int e6 = e5 + 131072;
  const int stride = gridDim.x * blockDim.x;
  for (int i = blockIdx.x * blockDim.x + threadIdx.x; i < e6; i += stride) {
    const float* s; __hip_bfloat16* d; int j;
    if (i < e0)      { s = s0; d = d0; j = i; }
    else if (i < e1) { s = s1; d = d1; j = i - e0; }
    else if (i < e2) { s = s2; d = d2; j = i - e1; }
    else if (i < e3) { s = s3; d = d3; j = i - e2; }
    else if (i < e4) { s = s4; d = d4; j = i - e3; }
    else if (i < e5) { s = s5; d = d5; j = i - e4; }
    else             { s = s6; d = d6; j = i - e5; }
    const float4 v = *(const float4*)(s + (size_t)j * 4);
    s16x4 o;
    __hip_bfloat16 h;
    h = __float2bfloat16(v.x); o[0] = *(short*)&h;
    h = __float2bfloat16(v.y); o[1] = *(short*)&h;
    h = __float2bfloat16(v.z); o[2] = *(short*)&h;
    h = __float2bfloat16(v.w); o[3] = *(short*)&h;
    *(s16x4*)((short*)d + (size_t)j * 4) = o;
  }
}

// LDS slot swizzle (proven: conflicts -> 0): LDS[row][slot] holds global chunk
// slot^((row>>1)&3); read slot for chunk lg: lg^((lr>>1)&3).

// C[M,N] = A[M,K] @ W[N,K]^T + bias. 128x128 tile, BK=32, 4 waves (m97 frame).
template <int RELU, int OUTMODE>
__global__ __launch_bounds__(256, 2) void gemm_bt(
    const __hip_bfloat16* __restrict__ Abf, const __hip_bfloat16* __restrict__ Wbf,
    const float* __restrict__ bias, void* __restrict__ Cv,
    int M, int N, int K) {
  __shared__ __align__(16) __hip_bfloat16 As[128 * 32];
  __shared__ __align__(16) __hip_bfloat16 Bs[128 * 32];
  const int t = threadIdx.x;
  const int w = t >> 6, lane = t & 63;
  const int lr = lane & 15, lg = lane >> 4;
  const int m0 = blockIdx.x * 128, n0 = blockIdx.y * 128;
  const int wr = (w >> 1) * 64, wc = (w & 1) * 64;

  const char* Ag = (const char*)Abf;
  const char* Wg = (const char*)Wbf;
  const size_t ldb = (size_t)K * 2;

  f32x4 acc[4][4] = {};

  const int o0 = (w << 10) + lane * 16;
  const int o1 = o0 + 4096;
  const int r0 = o0 >> 6, gc0 = ((((o0 >> 4) & 3) ^ ((r0 >> 1) & 3)) << 4);
  const int r1 = o1 >> 6, gc1 = ((((o1 >> 4) & 3) ^ ((r1 >> 1) & 3)) << 4);
  const int slx = (lg ^ ((lr >> 1) & 3)) << 4;

  for (int kt = 0; kt < K; kt += 32) {
    if (kt) __syncthreads();
    gload_lds16(Ag + (size_t)(m0 + r0) * ldb + kt * 2 + gc0, (char*)As + (w << 10));
    gload_lds16(Ag + (size_t)(m0 + r1) * ldb + kt * 2 + gc1, (char*)As + 4096 + (w << 10));
    gload_lds16(Wg + (size_t)(n0 + r0) * ldb + kt * 2 + gc0, (char*)Bs + (w << 10));
    gload_lds16(Wg + (size_t)(n0 + r1) * ldb + kt * 2 + gc1, (char*)Bs + 4096 + (w << 10));
    __syncthreads();

    bf16x8 af[4], bfv[4];
#pragma unroll
    for (int mi = 0; mi < 4; ++mi)
      af[mi] = *(const bf16x8*)((const char*)As + ((wr + mi * 16 + lr) << 6) + slx);
#pragma unroll
    for (int ni = 0; ni < 4; ++ni)
      bfv[ni] = *(const bf16x8*)((const char*)Bs + ((wc + ni * 16 + lr) << 6) + slx);
#pragma unroll
    for (int mi = 0; mi < 4; ++mi)
#pragma unroll
      for (int ni = 0; ni < 4; ++ni)
        acc[mi][ni] = MFMA16(af[mi], bfv[ni], acc[mi][ni]);
  }

#pragma unroll
  for (int ni = 0; ni < 4; ++ni) {
    const int col = n0 + wc + ni * 16 + lr;
    const float bv = bias[col];
#pragma unroll
    for (int mi = 0; mi < 4; ++mi) {
      const int row = m0 + wr + mi * 16 + lg * 4;
#pragma unroll
      for (int j = 0; j < 4; ++j) {
        float v = acc[mi][ni][j] + bv;
        if (RELU) v = fmaxf(v, 0.0f);
        if (OUTMODE == 0) {
          ((__hip_bfloat16*)Cv)[(size_t)(row + j) * N + col] = __float2bfloat16(v);
        } else if (OUTMODE == 1) {
          ((float*)Cv)[(size_t)(row + j) * N + col] = v;
        } else {
          const int rb = (row + j) >> 8, s = (row + j) & 255;
          const int hh = col >> 6, d = col & 63;
          ((__hip_bfloat16*)Cv)[(((size_t)(rb * 16 + hh) * 64 + d) << 8) + s] =
              __float2bfloat16(v);
        }
      }
    }
  }
}

// --- 256x256 LITE: 2-buffer 64KB -> 2 blocks/CU (round-13/14, proven) ---
__device__ __forceinline__ void gemm256_lite(
    const __hip_bfloat16* __restrict__ Abf, const __hip_bfloat16* __restrict__ Wbf,
    const float* __restrict__ bias, __hip_bfloat16* __restrict__ C,
    int N, int K, int outmode, int relu, int bx, int by) {
  __shared__ __align__(16) __hip_bfloat16 AsL[2][256 * 32];  // 2 x 16KB
  __shared__ __align__(16) __hip_bfloat16 BsL[2][256 * 32];  // 2 x 16KB
  const int t = threadIdx.x;
  const int w = t >> 6, lane = t & 63;
  const int lr = lane & 15, lg = lane >> 4;
  const int m0 = bx * 256, n0 = by * 256;
  const int wr = (w >> 2) * 128, wc = (w & 3) * 64;

  const char* Ag = (const char*)Abf;
  const char* Wg = (const char*)Wbf;
  const size_t ldb = (size_t)K * 2;

  f32x4 acc[8][4] = {};

  const int o0 = (w << 10) + lane * 16;
  const int o1 = o0 + 8192;
  const int r0 = o0 >> 6, gc0 = ((((o0 >> 4) & 3) ^ ((r0 >> 1) & 3)) << 4);
  const int r1 = o1 >> 6, gc1 = ((((o1 >> 4) & 3) ^ ((r1 >> 1) & 3)) << 4);
  const int slx = (lg ^ ((lr >> 1) & 3)) << 4;
  const int db0 = (w << 10);
  const int db1 = 8192 + (w << 10);

  auto STAGE_A = [&](int buf, int tile) {
    const int kt = tile << 5;
    gload_lds16(Ag + (size_t)(m0 + r0) * ldb + kt * 2 + gc0, (char*)AsL[buf] + db0);
    gload_lds16(Ag + (size_t)(m0 + r1) * ldb + kt * 2 + gc1, (char*)AsL[buf] + db1);
  };
  auto STAGE_B = [&](int buf, int tile) {
    const int kt = tile << 5;
    gload_lds16(Wg + (size_t)(n0 + r0) * ldb + kt * 2 + gc0, (char*)BsL[buf] + db0);
    gload_lds16(Wg + (size_t)(n0 + r1) * ldb + kt * 2 + gc1, (char*)BsL[buf] + db1);
  };

  const int nt = K >> 5;
  STAGE_A(0, 0); STAGE_B(0, 0);
  asm volatile("s_waitcnt vmcnt(0)" ::: "memory");
  asm volatile("s_barrier" ::: "memory");
  for (int j = 0; j < nt; ++j) {
    const int buf = j & 1;
    const int stage = (j + 1 < nt);
    bf16x8 af0[4], af1[4], bfv[4];
    // phase 0
#pragma unroll
    for (int mi = 0; mi < 4; ++mi)
      af0[mi] = *(const bf16x8*)((const char*)AsL[buf] + ((wr + mi * 16 + lr) << 6) + slx);
#pragma unroll
    for (int ni = 0; ni < 4; ++ni)
      bfv[ni] = *(const bf16x8*)((const char*)BsL[buf] + ((wc + ni * 16 + lr) << 6) + slx);
    if (stage) STAGE_A(buf ^ 1, j + 1);
    asm volatile("s_barrier" ::: "memory");
    asm volatile("s_waitcnt lgkmcnt(0)" ::: "memory");
    __builtin_amdgcn_sched_barrier(0);
    __builtin_amdgcn_s_setprio(1);
#pragma unroll
    for (int mi = 0; mi < 4; ++mi)
#pragma unroll
      for (int ni = 0; ni < 4; ++ni)
        acc[mi][ni] = MFMA16(af0[mi], bfv[ni], acc[mi][ni]);
    __builtin_amdgcn_s_setprio(0);
    asm volatile("s_barrier" ::: "memory");
    // phase 1
#pragma unroll
    for (int mi = 0; mi < 4; ++mi)
      af1[mi] = *(const bf16x8*)((const char*)AsL[buf] + ((wr + (mi + 4) * 16 + lr) << 6) + slx);
    if (stage) STAGE_B(buf ^ 1, j + 1);
    asm volatile("s_barrier" ::: "memory");
    asm volatile("s_waitcnt lgkmcnt(0)" ::: "memory");
    __builtin_amdgcn_sched_barrier(0);
    __builtin_amdgcn_s_setprio(1);
#pragma unroll
    for (int mi = 0; mi < 4; ++mi)
#pragma unroll
      for (int ni = 0; ni < 4; ++ni)
        acc[mi + 4][ni] = MFMA16(af1[mi], bfv[ni], acc[mi + 4][ni]);
    __builtin_amdgcn_s_setprio(0);
    if (stage) asm volatile("s_waitcnt vmcnt(0)" ::: "memory");
    asm volatile("s_barrier" ::: "memory");
  }

#pragma unroll
  for (int ni = 0; ni < 4; ++ni) {
    const int col = n0 + wc + ni * 16 + lr;
    const float bv = bias[col];
#pragma unroll
    for (int mi = 0; mi < 8; ++mi) {
      const int row = m0 + wr + mi * 16 + lg * 4;
#pragma unroll
      for (int j = 0; j < 4; ++j) {
        float v = acc[mi][ni][j] + bv;
        if (relu) v = fmaxf(v, 0.0f);
        if (outmode == 0) {
          C[(size_t)(row + j) * N + col] = __float2bfloat16(v);
        } else {
          const int rb = (row + j) >> 8, s = (row + j) & 255;
          const int hh = col >> 6, d = col & 63;
          C[(((size_t)(rb * 16 + hh) * 64 + d) << 8) + s] = __float2bfloat16(v);
        }
      }
    }
  }
}

// --- 128x256 LITE: half-size blocks for load balance. Same protocol;
// LDS 48KB (A 2x8KB + B 2x16KB) -> 2 blocks/CU; acc[4][4].
__device__ __forceinline__ void gemm128_lite(
    const __hip_bfloat16* __restrict__ Abf, const __hip_bfloat16* __restrict__ Wbf,
    const float* __restrict__ bias, __hip_bfloat16* __restrict__ C,
    int N, int K, int outmode, int relu, int bx, int by) {
  __shared__ __align__(16) __hip_bfloat16 AsL[2][128 * 32];  // 2 x 8KB
  __shared__ __align__(16) __hip_bfloat16 BsL[2][256 * 32];  // 2 x 16KB
  const int t = threadIdx.x;
  const int w = t >> 6, lane = t & 63;
  const int lr = lane & 15, lg = lane >> 4;
  const int m0 = bx * 128, n0 = by * 256;
  const int wr = (w >> 2) * 64, wc = (w & 3) * 64;  // per-wave 64x64

  const char* Ag = (const char*)Abf;
  const char* Wg = (const char*)Wbf;
  const size_t ldb = (size_t)K * 2;

  f32x4 acc[4][4] = {};

  const int o0 = (w << 10) + lane * 16;   // 0..8191: A single pass / B pass 0
  const int o1 = o0 + 8192;               // B pass 1
  const int r0 = o0 >> 6, gc0 = ((((o0 >> 4) & 3) ^ ((r0 >> 1) & 3)) << 4);
  const int r1 = o1 >> 6, gc1 = ((((o1 >> 4) & 3) ^ ((r1 >> 1) & 3)) << 4);
  const int slx = (lg ^ ((lr >> 1) & 3)) << 4;
  const int db0 = (w << 10);
  const int db1 = 8192 + (w << 10);

  auto STAGE_A = [&](int buf, int tile) {   // 8KB: one pass
    const int kt = tile << 5;
    gload_lds16(Ag + (size_t)(m0 + r0) * ldb + kt * 2 + gc0, (char*)AsL[buf] + db0);
  };
  auto STAGE_B = [&](int buf, int tile) {   // 16KB: two passes
    const int kt = tile << 5;
    gload_lds16(Wg + (size_t)(n0 + r0) * ldb + kt * 2 + gc0, (char*)BsL[buf] + db0);
    gload_lds16(Wg + (size_t)(n0 + r1) * ldb + kt * 2 + gc1, (char*)BsL[buf] + db1);
  };

  const int nt = K >> 5;
  STAGE_A(0, 0); STAGE_B(0, 0);
  asm volatile("s_waitcnt vmcnt(0)" ::: "memory");
  asm volatile("s_barrier" ::: "memory");
  for (int j = 0; j < nt; ++j) {
    const int buf = j & 1;
    const int stage = (j + 1 < nt);
    bf16x8 af0[2], af1[2], bfv[4];
    // phase 0: mi 0..1
#pragma unroll
    for (int mi = 0; mi < 2; ++mi)
      af0[mi] = *(const bf16x8*)((const char*)AsL[buf] + ((wr + mi * 16 + lr) << 6) + slx);
#pragma unroll
    for (int ni = 0; ni < 4; ++ni)
      bfv[ni] = *(const bf16x8*)((const char*)BsL[buf] + ((wc + ni * 16 + lr) << 6) + slx);
    if (stage) STAGE_A(buf ^ 1, j + 1);
    asm volatile("s_barrier" ::: "memory");
    asm volatile("s_waitcnt lgkmcnt(0)" ::: "memory");
    __builtin_amdgcn_sched_barrier(0);
    __builtin_amdgcn_s_setprio(1);
#pragma unroll
    for (int mi = 0; mi < 2; ++mi)
#pragma unroll
      for (int ni = 0; ni < 4; ++ni)
        acc[mi][ni] = MFMA16(af0[mi], bfv[ni], acc[mi][ni]);
    __builtin_amdgcn_s_setprio(0);
    asm volatile("s_barrier" ::: "memory");
    // phase 1: mi 2..3
#pragma unroll
    for (int mi = 0; mi < 2; ++mi)
      af1[mi] = *(const bf16x8*)((const char*)AsL[buf] + ((wr + (mi + 2) * 16 + lr) << 6) + slx);
    if (stage) STAGE_B(buf ^ 1, j + 1);
    asm volatile("s_barrier" ::: "memory");
    asm volatile("s_waitcnt lgkmcnt(0)" ::: "memory");
    __builtin_amdgcn_sched_barrier(0);
    __builtin_amdgcn_s_setprio(1);
#pragma unroll
    for (int mi = 0; mi < 2; ++mi)
#pragma unroll
      for (int ni = 0; ni < 4; ++ni)
        acc[mi + 2][ni] = MFMA16(af1[mi], bfv[ni], acc[mi + 2][ni]);
    __builtin_amdgcn_s_setprio(0);
    if (stage) asm volatile("s_waitcnt vmcnt(0)" ::: "memory");
    asm volatile("s_barrier" ::: "memory");
  }

#pragma unroll
  for (int ni = 0; ni < 4; ++ni) {
    const int col = n0 + wc + ni * 16 + lr;
    const float bv = bias[col];
#pragma unroll
    for (int mi = 0; mi < 4; ++mi) {
      const int row = m0 + wr + mi * 16 + lg * 4;
#pragma unroll
      for (int j = 0; j < 4; ++j) {
        float v = acc[mi][ni][j] + bv;
        if (relu) v = fmaxf(v, 0.0f);
        if (outmode == 0) {
          C[(size_t)(row + j) * N + col] = __float2bfloat16(v);
        } else {
          const int rb = (row + j) >> 8, s = (row + j) & 255;
          const int hh = col >> 6, d = col & 63;
          C[(((size_t)(rb * 16 + hh) * 64 + d) << 8) + s] = __float2bfloat16(v);
        }
      }
    }
  }
}

// Q, K, V projections in ONE launch: 576 half-size (128x256) blocks ->
// uniform block duration, 512 co-resident slots, ~1.1 scheduling rounds
// (vs 288 full-size blocks = 2 rounds with 224 CUs half-idle).
__global__ __launch_bounds__(512, 4) void gemm256_qkv(
    const __hip_bfloat16* __restrict__ xb, const __hip_bfloat16* __restrict__ ctxb,
    const __hip_bfloat16* __restrict__ Wq, const __hip_bfloat16* __restrict__ Wk,
    const __hip_bfloat16* __restrict__ Wv,
    const float* __restrict__ bq, const float* __restrict__ bk, const float* __restrict__ bv,
    __hip_bfloat16* __restrict__ Q, __hip_bfloat16* __restrict__ Kp,
    __hip_bfloat16* __restrict__ Vt) {
  const int bid = blockIdx.x;
  if (bid < 32) {         // K-proj: 8 m-tiles x 4 n-tiles
    gemm128_lite(ctxb, Wk, bk, Kp, 1024, 768, 0, 0, bid >> 2, bid & 3);
  } else if (bid < 64) {  // V-proj (V^T out)
    const int l = bid - 32;
    gemm128_lite(ctxb, Wv, bv, Vt, 1024, 768, 2, 0, l >> 2, l & 3);
  } else {                // Q-proj: 128 m-tiles x 4 n-tiles, XCD-chunked
    const int l = bid - 64;                      // 0..511; l%8 = XCD id
    const int rb = (l & 7) * 64 + (l >> 3);      // bijective (512 % 8 == 0)
    gemm128_lite(xb, Wq, bq, Q, 1024, 512, 0, 0, rb >> 2, rb & 3);
  }
}

// P1 (ReLU): 256^2 LITE body (proven ~820 TF), XCD-chunked remap.
__global__ __launch_bounds__(512, 2) void gemm256_p1(
    const __hip_bfloat16* __restrict__ A, const __hip_bfloat16* __restrict__ W,
    const float* __restrict__ bias, __hip_bfloat16* __restrict__ C) {
  const int bid = blockIdx.x;  // 256 blocks
  const int rb = (bid & 7) * 32 + (bid >> 3);
  gemm256_lite(A, W, bias, C, 1024, 1024, 0, 1, rb >> 2, rb & 3);
}

// Fused cross-attention (round-10, frozen): 8 waves/block, swapped QK^T,
// register P, 16x16x16 PV.
__global__ __launch_bounds__(512, 4) void attn_fused(
    const __hip_bfloat16* __restrict__ Qb, const __hip_bfloat16* __restrict__ Kb,
    const __hip_bfloat16* __restrict__ Vtg, const float* __restrict__ padm,
    const float* __restrict__ seqm, __hip_bfloat16* __restrict__ O) {
  constexpr int S = 256, E = 1024, Nq = 4096;
  constexpr float NEGV = -1e9f;
  __shared__ __align__(16) char smem[65536];
  char* VtB = smem;
  char* KsB = smem + 32768;

  const int t = threadIdx.x;           // 0..511
  const int w = t >> 6, lane = t & 63; // 8 waves
  const int lr = lane & 15, lg = lane >> 4;
  const int h = blockIdx.y, b = blockIdx.z;

  const char* Kg = (const char*)(Kb + (size_t)b * S * E + h * 64);
#pragma unroll
  for (int i = 0; i < 4; ++i) {
    const int o = ((i * 8 + w) << 10) + lane * 16;
    const int s = o >> 7, bc = o & 127;
    gload_lds16(Kg + (size_t)s * (E * 2) + (bc ^ ((s & 7) << 4)), KsB + ((i * 8 + w) << 10));
  }
  const char* Vg = (const char*)Vtg + ((size_t)(b * 16 + h) << 15);
#pragma unroll
  for (int i = 0; i < 4; ++i) {
    const int o = ((i * 8 + w) << 10) + lane * 16;
    const int d = o >> 9, c = o & 511;
    gload_lds16(Vg + (d << 9) + (c ^ ((d & 7) << 4)), VtB + ((i * 8 + w) << 10));
  }

  const int qw = blockIdx.x * 128 + w * 16;
  const short* Qg = (const short*)Qb + (size_t)(b * Nq + qw + lr) * E + h * 64;
  const bf16x8 aq0 = *(const bf16x8*)(Qg + (lg << 3));
  const bf16x8 aq1 = *(const bf16x8*)(Qg + 32 + (lg << 3));
  const float padq = padm[(size_t)b * Nq + qw + lr];
  const float qbias = (padq != 0.f) ? 0.f : NEGV;

  __syncthreads();

  const int swz = (lr & 7) << 4;
  f32x4 o[4] = {};
  float ssum = 0.f;
#pragma unroll
  for (int ni = 0; ni < 16; ++ni) {
    const int s = ni * 16 + lr;
    const bf16x8 bk0 = *(const bf16x8*)(KsB + (s << 7) + ((lg << 4) ^ swz));
    const bf16x8 bk1 = *(const bf16x8*)(KsB + (s << 7) + ((64 + (lg << 4)) ^ swz));
    f32x4 a = {};
    a = MFMA16(bk0, aq0, a);
    a = MFMA16(bk1, aq1, a);

    const float4 sm4 = *(const float4*)(seqm + (size_t)b * S + ni * 16 + lg * 4);
    const float e0 = __expf(a[0] * 0.125f + ((sm4.x != 0.f ? 0.f : NEGV) + qbias));
    const float e1 = __expf(a[1] * 0.125f + ((sm4.y != 0.f ? 0.f : NEGV) + qbias));
    const float e2 = __expf(a[2] * 0.125f + ((sm4.z != 0.f ? 0.f : NEGV) + qbias));
    const float e3 = __expf(a[3] * 0.125f + ((sm4.w != 0.f ? 0.f : NEGV) + qbias));
    ssum += (e0 + e1) + (e2 + e3);

    s16x4 pf;
    __hip_bfloat16 hh;
    hh = __float2bfloat16(e0); pf[0] = *(short*)&hh;
    hh = __float2bfloat16(e1); pf[1] = *(short*)&hh;
    hh = __float2bfloat16(e2); pf[2] = *(short*)&hh;
    hh = __float2bfloat16(e3); pf[3] = *(short*)&hh;

    const int sb = (ni * 32 + lg * 8);
#pragma unroll
    for (int nd = 0; nd < 4; ++nd) {
      const int d = nd * 16 + lr;
      const s16x4 bv = *(const s16x4*)(VtB + (d << 9) + (sb ^ swz));
      o[nd] = MFMAH(pf, bv, o[nd]);
    }
  }

  ssum += __shfl_xor(ssum, 16);
  ssum += __shfl_xor(ssum, 32);
  const float inv = 1.0f / ssum;
  float invj[4];
#pragma unroll
  for (int j = 0; j < 4; ++j) invj[j] = __shfl(inv, lg * 4 + j);

  __hip_bfloat16* Og = O + (size_t)(b * Nq + qw) * E + h * 64;
#pragma unroll
  for (int nd = 0; nd < 4; ++nd)
#pragma unroll
    for (int j = 0; j < 4; ++j)
      Og[(size_t)(lg * 4 + j) * E + nd * 16 + lr] = __float2bfloat16(o[nd][j] * invj[j]);
}

extern "C" void kernel_launch(void* const* d_in, const int* in_sizes, int n_in,
                              void* d_out, int out_size, void* d_ws, size_t ws_size,
                              hipStream_t stream) {
  const float* x    = (const float*)d_in[0];
  const float* ctx  = (const float*)d_in[1];
  const float* padm = (const float*)d_in[2];
  const float* seqm = (const float*)d_in[3];
  const float* Wq_w = (const float*)d_in[4];
  const float* Wq_b = (const float*)d_in[5];
  const float* Wk_w = (const float*)d_in[6];
  const float* Wk_b = (const float*)d_in[7];
  const float* Wv_w = (const float*)d_in[8];
  const float* Wv_b = (const float*)d_in[9];
  const float* P1_w = (const float*)d_in[10];
  const float* P1_b = (const float*)d_in[11];
  const float* P2_w = (const float*)d_in[12];
  const float* P2_b = (const float*)d_in[13];
  float* out = (float*)d_out;

  char* ws = (char*)d_ws;
  size_t off = 0;
  auto alloc = [&](size_t bytes) { char* p = ws + off; off += (bytes + 255) & ~(size_t)255; return p; };
  __hip_bfloat16* Q    = (__hip_bfloat16*)alloc(16384ull * 1024 * 2);  // 32MB (later O1)
  __hip_bfloat16* AO   = (__hip_bfloat16*)alloc(16384ull * 1024 * 2);  // 32MB
  __hip_bfloat16* xb   = (__hip_bfloat16*)alloc(16384ull * 512 * 2);   // 16MB
  __hip_bfloat16* ctxb = (__hip_bfloat16*)alloc(1024ull * 768 * 2);
  __hip_bfloat16* Kp   = (__hip_bfloat16*)alloc(1024ull * 1024 * 2);
  __hip_bfloat16* Vt   = (__hip_bfloat16*)alloc(1024ull * 1024 * 2);   // V^T [b,h][d][s]
  __hip_bfloat16* Wqb  = (__hip_bfloat16*)alloc(1024ull * 512 * 2);
  __hip_bfloat16* Wkb  = (__hip_bfloat16*)alloc(1024ull * 768 * 2);
  __hip_bfloat16* Wvb  = (__hip_bfloat16*)alloc(1024ull * 768 * 2);
  __hip_bfloat16* P1b  = (__hip_bfloat16*)alloc(1024ull * 1024 * 2);
  __hip_bfloat16* P2b  = (__hip_bfloat16*)alloc(512ull * 1024 * 2);
  __hip_bfloat16* O1   = Q;  // reuse Q after attention

  cvt_all<<<dim3(2048, 1, 1), dim3(256, 1, 1), 0, stream>>>(
      x, ctx, Wq_w, Wk_w, Wv_w, P1_w, P2_w, xb, ctxb, Wqb, Wkb, Wvb, P1b, P2b);

  gemm256_qkv<<<dim3(576, 1, 1), dim3(512, 1, 1), 0, stream>>>(
      xb, ctxb, Wqb, Wkb, Wvb, Wq_b, Wk_b, Wv_b, Q, Kp, Vt);
  attn_fused<<<dim3(32, 16, 4), dim3(512, 1, 1), 0, stream>>>(Q, Kp, Vt, padm, seqm, AO);
  gemm256_p1<<<dim3(256, 1, 1), dim3(512, 1, 1), 0, stream>>>(AO, P1b, P1_b, O1);
  gemm_bt<0, 1><<<dim3(128, 4, 1), dim3(256, 1, 1), 0, stream>>>(O1, P2b, P2_b, out, 16384, 512, 1024);
}